// Round 7
// baseline (3026.928 us; speedup 1.0000x reference)
//
#include <hip/hip_runtime.h>
#include <hip/hip_bf16.h>

#define NN 100000
#define EE 1600000
#define GG 1000
#define DIMH 256
#define NDEPTH 4
#define NBUCK 391          // ceil(NN/256) buckets of 256 dst nodes
#define LDSROWS 144        // statsnorm LDS row cache
static constexpr float EPSV = 1e-5f;

typedef unsigned short ushort;
typedef __attribute__((ext_vector_type(8))) short short8v;
typedef __attribute__((ext_vector_type(4))) float f32x4;

__device__ __forceinline__ float bf2f(ushort u) {
    return __uint_as_float(((unsigned)u) << 16);
}
__device__ __forceinline__ ushort f2bf(float f) {
    unsigned u = __float_as_uint(f);
    unsigned r = u + 0x7FFFu + ((u >> 16) & 1u);   // RNE
    return (ushort)(r >> 16);
}

#define GLOAD16(g, s) __builtin_amdgcn_global_load_lds((const __attribute__((address_space(1))) void*)(g), \
                      (__attribute__((address_space(3))) void*)(s), 16, 0, 0)

// ---------------- CSR build ----------------
__global__ __launch_bounds__(256) void k_graph_bounds(const int* __restrict__ batch, int* __restrict__ gstart) {
    int g = blockIdx.x * 256 + threadIdx.x;
    if (g > GG) return;
    int lo = 0, hi = NN;
    while (lo < hi) { int mid = (lo + hi) >> 1; if (batch[mid] < g) lo = mid + 1; else hi = mid; }
    gstart[g] = lo;
}

// bucket histogram over dst>>8
__global__ __launch_bounds__(256) void k_bhist(const int* __restrict__ dst, int* __restrict__ bcnt) {
    int e = blockIdx.x * 256 + threadIdx.x;
    if (e < EE) atomicAdd(&bcnt[dst[e] >> 8], 1);
}

// single-block scan of NBUCK buckets -> bstart (exclusive) + bcursor copy
__global__ __launch_bounds__(512) void k_bscan(const int* __restrict__ bcnt, int* __restrict__ bstart,
                                               int* __restrict__ bcursor) {
    __shared__ int s[512];
    int t = threadIdx.x;
    int v = (t < NBUCK) ? bcnt[t] : 0;
    s[t] = v; __syncthreads();
    for (int off = 1; off < 512; off <<= 1) {
        int u = (t >= off) ? s[t - off] : 0;
        __syncthreads();
        s[t] += u;
        __syncthreads();
    }
    if (t < NBUCK) { int ex = s[t] - v; bstart[t] = ex; bcursor[t] = ex; }
    if (t == 0) bstart[NBUCK] = EE;
}

// partition edges into bucket-ordered pair array; also dst-degree histogram
__global__ __launch_bounds__(256) void k_bscatter(const int* __restrict__ src, const int* __restrict__ dst,
                                                  int* __restrict__ bcursor, int2* __restrict__ ebuf,
                                                  int* __restrict__ deg) {
    int e = blockIdx.x * 256 + threadIdx.x;
    if (e >= EE) return;
    int d = dst[e];
    int pos = atomicAdd(&bcursor[d >> 8], 1);
    ebuf[pos] = make_int2(src[e], d);
    atomicAdd(&deg[d], 1);
}

__global__ __launch_bounds__(256) void k_scan_a(const int* __restrict__ deg, int* __restrict__ rs, int* __restrict__ part) {
    __shared__ int s[256];
    int t = threadIdx.x;
    int i = blockIdx.x * 256 + t;
    int v = (i < NN) ? deg[i] : 0;
    s[t] = v; __syncthreads();
    for (int off = 1; off < 256; off <<= 1) {
        int u = (t >= off) ? s[t - off] : 0;
        __syncthreads();
        s[t] += u;
        __syncthreads();
    }
    if (i < NN) rs[i] = s[t] - v;
    if (t == 255) part[blockIdx.x] = s[255];
}

__global__ __launch_bounds__(512) void k_scan_b(int* __restrict__ part, int nb, int* __restrict__ rs) {
    __shared__ int s[512];
    int t = threadIdx.x;
    int v = (t < nb) ? part[t] : 0;
    s[t] = v; __syncthreads();
    for (int off = 1; off < 512; off <<= 1) {
        int u = (t >= off) ? s[t - off] : 0;
        __syncthreads();
        s[t] += u;
        __syncthreads();
    }
    if (t < nb) part[t] = s[t] - v;  // exclusive
    if (t == 0) rs[NN] = EE;
}

// finalize row starts AND copy to cursor (deg reused as cursor)
__global__ __launch_bounds__(256) void k_scan_c(int* __restrict__ rs, const int* __restrict__ part,
                                                int* __restrict__ cursor) {
    int i = blockIdx.x * 256 + threadIdx.x;
    if (i < NN) {
        int v = rs[i] + part[blockIdx.x];
        rs[i] = v;
        cursor[i] = v;
    }
}

// within-bucket scatter: col writes land in ~16KB windows (L2-line friendly)
__global__ __launch_bounds__(256) void k_scatter2(const int2* __restrict__ ebuf, int* __restrict__ cursor,
                                                  int* __restrict__ col) {
    int e = blockIdx.x * 256 + threadIdx.x;
    if (e >= EE) return;
    int2 p = ebuf[e];
    int pos = atomicAdd(&cursor[p.y], 1);
    col[pos] = p.x;
}

// ---------------- weight transpose + bf16 split: W[K][N] f32 -> Wt_hi/lo[N][K] bf16 ----------------
__global__ __launch_bounds__(256) void k_wtrans(const float* __restrict__ in, ushort* __restrict__ out_hi,
                                                ushort* __restrict__ out_lo, int K, int N) {
    int d = blockIdx.z;
    in  += (size_t)d * K * N;
    out_hi += (size_t)d * K * N;
    out_lo += (size_t)d * K * N;
    int n0 = blockIdx.x * 32, k0 = blockIdx.y * 32;
    int t = threadIdx.x;
    int tx = t & 31, ty = t >> 5;      // ty 0..7
    __shared__ float tile[32][33];
#pragma unroll
    for (int j = 0; j < 4; j++) tile[ty + 8 * j][tx] = in[(size_t)(k0 + ty + 8 * j) * N + n0 + tx];
    __syncthreads();
#pragma unroll
    for (int j = 0; j < 4; j++) {
        float f = tile[tx][ty + 8 * j];
        ushort hi = f2bf(f);
        float lo = f - bf2f(hi);
        size_t o = (size_t)(n0 + ty + 8 * j) * K + k0 + tx;
        out_hi[o] = hi;
        out_lo[o] = f2bf(lo);
    }
}

// ---------------- node encoder ----------------
__global__ __launch_bounds__(256) void k_encoder(const int* __restrict__ xidx, const int* __restrict__ ndep,
                                                 const float* __restrict__ en, const float* __restrict__ ed,
                                                 ushort* __restrict__ x) {
    int gi = blockIdx.x * 256 + threadIdx.x;     // = node*64 + q
    int node = gi >> 6, q = gi & 63;
    if (node >= NN) return;
    float4 va = ((const float4*)en)[(size_t)xidx[node] * 64 + q];
    float4 vb = ((const float4*)ed)[(size_t)ndep[node] * 64 + q];
    ushort4 o;
    o.x = f2bf(va.x + vb.x); o.y = f2bf(va.y + vb.y);
    o.z = f2bf(va.z + vb.z); o.w = f2bf(va.w + vb.w);
    ((ushort4*)x)[gi] = o;
}

// ---------------- GIN aggregate (8 gathers in flight, 4 accumulator chains) ----------------
__global__ __launch_bounds__(256) void k_aggregate(const ushort* __restrict__ x, const int* __restrict__ rs,
                                                   const int* __restrict__ col, ushort* __restrict__ hb) {
    int node = blockIdx.x * 4 + (threadIdx.x >> 6);
    int lane = threadIdx.x & 63;
    if (node >= NN) return;
    const ushort4* x4 = (const ushort4*)x;
    ushort4 sv = x4[(size_t)node * 64 + lane];
    float a0 = bf2f(sv.x), a1 = bf2f(sv.y), a2 = bf2f(sv.z), a3 = bf2f(sv.w);
    float b0 = 0.f, b1 = 0.f, b2 = 0.f, b3 = 0.f;
    float c0 = 0.f, c1 = 0.f, c2 = 0.f, c3 = 0.f;
    float d0 = 0.f, d1 = 0.f, d2 = 0.f, d3 = 0.f;
    int s = rs[node], e = rs[node + 1];
    int j = s;
    for (; j + 8 <= e; j += 8) {
        int i0 = col[j], i1 = col[j + 1], i2 = col[j + 2], i3 = col[j + 3];
        int i4 = col[j + 4], i5 = col[j + 5], i6 = col[j + 6], i7 = col[j + 7];
        ushort4 v0 = x4[(size_t)i0 * 64 + lane];
        ushort4 v1 = x4[(size_t)i1 * 64 + lane];
        ushort4 v2 = x4[(size_t)i2 * 64 + lane];
        ushort4 v3 = x4[(size_t)i3 * 64 + lane];
        ushort4 v4 = x4[(size_t)i4 * 64 + lane];
        ushort4 v5 = x4[(size_t)i5 * 64 + lane];
        ushort4 v6 = x4[(size_t)i6 * 64 + lane];
        ushort4 v7 = x4[(size_t)i7 * 64 + lane];
        a0 += bf2f(v0.x); a1 += bf2f(v0.y); a2 += bf2f(v0.z); a3 += bf2f(v0.w);
        b0 += bf2f(v1.x); b1 += bf2f(v1.y); b2 += bf2f(v1.z); b3 += bf2f(v1.w);
        c0 += bf2f(v2.x); c1 += bf2f(v2.y); c2 += bf2f(v2.z); c3 += bf2f(v2.w);
        d0 += bf2f(v3.x); d1 += bf2f(v3.y); d2 += bf2f(v3.z); d3 += bf2f(v3.w);
        a0 += bf2f(v4.x); a1 += bf2f(v4.y); a2 += bf2f(v4.z); a3 += bf2f(v4.w);
        b0 += bf2f(v5.x); b1 += bf2f(v5.y); b2 += bf2f(v5.z); b3 += bf2f(v5.w);
        c0 += bf2f(v6.x); c1 += bf2f(v6.y); c2 += bf2f(v6.z); c3 += bf2f(v6.w);
        d0 += bf2f(v7.x); d1 += bf2f(v7.y); d2 += bf2f(v7.z); d3 += bf2f(v7.w);
    }
    for (; j + 4 <= e; j += 4) {
        int i0 = col[j], i1 = col[j + 1], i2 = col[j + 2], i3 = col[j + 3];
        ushort4 v0 = x4[(size_t)i0 * 64 + lane];
        ushort4 v1 = x4[(size_t)i1 * 64 + lane];
        ushort4 v2 = x4[(size_t)i2 * 64 + lane];
        ushort4 v3 = x4[(size_t)i3 * 64 + lane];
        a0 += bf2f(v0.x); a1 += bf2f(v0.y); a2 += bf2f(v0.z); a3 += bf2f(v0.w);
        b0 += bf2f(v1.x); b1 += bf2f(v1.y); b2 += bf2f(v1.z); b3 += bf2f(v1.w);
        c0 += bf2f(v2.x); c1 += bf2f(v2.y); c2 += bf2f(v2.z); c3 += bf2f(v2.w);
        d0 += bf2f(v3.x); d1 += bf2f(v3.y); d2 += bf2f(v3.z); d3 += bf2f(v3.w);
    }
    for (; j < e; j++) {
        int c = col[j];
        ushort4 v = x4[(size_t)c * 64 + lane];
        a0 += bf2f(v.x); a1 += bf2f(v.y); a2 += bf2f(v.z); a3 += bf2f(v.w);
    }
    a0 += b0 + c0 + d0; a1 += b1 + c1 + d1; a2 += b2 + c2 + d2; a3 += b3 + c3 + d3;
    ushort4 o; o.x = f2bf(a0); o.y = f2bf(a1); o.z = f2bf(a2); o.w = f2bf(a3);
    ((ushort4*)hb)[(size_t)node * 64 + lane] = o;
}

// ============ GEMM v4: block 256x128, 4 waves of 128x64, K_STEP=64, stage->barrier->compute ============
// MODE 0: bias, store bf16.  MODE 1: bias+relu, store bf16.  MODE 2: attgate partial -> partial[row][by*2+wc]
template<int MODE>
__global__ __launch_bounds__(256, 2) void k_gemm64(const ushort* __restrict__ A,
                                                   const ushort* __restrict__ Bhi,
                                                   const ushort* __restrict__ Blo,
                                                   const float* __restrict__ bias,
                                                   const float* __restrict__ w2,
                                                   ushort* __restrict__ C,
                                                   float* __restrict__ partial,
                                                   int M) {
    __shared__ __align__(16) ushort As[256 * 64];   // 32 KB
    __shared__ __align__(16) ushort Bh[128 * 64];   // 16 KB
    __shared__ __align__(16) ushort Bl[128 * 64];   // 16 KB
    int t = threadIdx.x;
    int wv = t >> 6, l = t & 63;
    int wr = wv >> 1, wc = wv & 1;
    int row0 = blockIdx.x * 256;
    int col0 = blockIdx.y * 128;

    f32x4 acc[8][4];
#pragma unroll
    for (int m = 0; m < 8; m++)
#pragma unroll
        for (int n = 0; n < 4; n++) acc[m][n] = (f32x4){0.f, 0.f, 0.f, 0.f};

    int srow_in = l >> 3;       // 0..7
    int slot    = l & 7;        // 16B chunk slot within a 128B row

    for (int k0 = 0; k0 < 256; k0 += 64) {
#pragma unroll
        for (int i = 0; i < 8; i++) {
            int stripe = wv * 8 + i;                // 0..31
            int rl = stripe * 8 + srow_in;          // 0..255
            int gc = slot ^ (rl & 7);               // pre-swizzled global chunk
            const ushort* ga = A + (size_t)min(row0 + rl, M - 1) * 256 + k0 + gc * 8;
            GLOAD16(ga, As + stripe * 512 + l * 8);
        }
#pragma unroll
        for (int i = 0; i < 4; i++) {
            int stripe = wv * 4 + i;                // 0..15
            int rl = stripe * 8 + srow_in;          // 0..127
            int gc = slot ^ (rl & 7);
            const ushort* gh = Bhi + (size_t)(col0 + rl) * 256 + k0 + gc * 8;
            GLOAD16(gh, Bh + stripe * 512 + l * 8);
            const ushort* gl = Blo + (size_t)(col0 + rl) * 256 + k0 + gc * 8;
            GLOAD16(gl, Bl + stripe * 512 + l * 8);
        }
        __syncthreads();
#pragma unroll
        for (int s = 0; s < 2; s++) {
            short8v af[8], bhf[4], blf[4];
#pragma unroll
            for (int m = 0; m < 8; m++) {
                int r = wr * 128 + m * 16 + (l & 15);
                int ch = (s * 4 + (l >> 4)) ^ (r & 7);
                af[m] = *(const short8v*)(As + r * 64 + ch * 8);
            }
#pragma unroll
            for (int n = 0; n < 4; n++) {
                int rb = wc * 64 + n * 16 + (l & 15);
                int ch = (s * 4 + (l >> 4)) ^ (rb & 7);
                bhf[n] = *(const short8v*)(Bh + rb * 64 + ch * 8);
                blf[n] = *(const short8v*)(Bl + rb * 64 + ch * 8);
            }
#pragma unroll
            for (int m = 0; m < 8; m++)
#pragma unroll
                for (int n = 0; n < 4; n++) {
                    acc[m][n] = __builtin_amdgcn_mfma_f32_16x16x32_bf16(af[m], bhf[n], acc[m][n], 0, 0, 0);
                    acc[m][n] = __builtin_amdgcn_mfma_f32_16x16x32_bf16(af[m], blf[n], acc[m][n], 0, 0, 0);
                }
        }
        __syncthreads();
    }

    int lr = l & 15, kc = l >> 4;
    if (MODE == 2) {
        float b1v[4], w2v[4];
#pragma unroll
        for (int n = 0; n < 4; n++) {
            int colc = col0 + wc * 64 + n * 16 + lr;
            b1v[n] = bias[colc];
            w2v[n] = w2[colc];
        }
#pragma unroll
        for (int m = 0; m < 8; m++) {
#pragma unroll
            for (int j = 0; j < 4; j++) {
                float p = 0.f;
#pragma unroll
                for (int n = 0; n < 4; n++) {
                    float v = fmaxf(acc[m][n][j] + b1v[n], 0.f);
                    p = fmaf(v, w2v[n], p);
                }
#pragma unroll
                for (int off = 1; off < 16; off <<= 1) p += __shfl_xor(p, off, 64);
                if (lr == 0) {
                    int row = row0 + wr * 128 + m * 16 + (kc << 2) + j;
                    if (row < M) partial[(size_t)row * 8 + blockIdx.y * 2 + wc] = p;
                }
            }
        }
    } else {
        float bv[4];
#pragma unroll
        for (int n = 0; n < 4; n++) bv[n] = bias[col0 + wc * 64 + n * 16 + lr];
#pragma unroll
        for (int m = 0; m < 8; m++) {
#pragma unroll
            for (int j = 0; j < 4; j++) {
                int row = row0 + wr * 128 + m * 16 + (kc << 2) + j;
                if (row < M) {
#pragma unroll
                    for (int n = 0; n < 4; n++) {
                        float v = acc[m][n][j] + bv[n];
                        if (MODE == 1) v = fmaxf(v, 0.f);
                        C[(size_t)row * 256 + col0 + wc * 64 + n * 16 + lr] = f2bf(v);
                    }
                }
            }
        }
    }
}

// ---------------- gate finisher ----------------
__global__ __launch_bounds__(256) void k_gatefin(const float* __restrict__ partial, const float* __restrict__ b2,
                                                 float* __restrict__ gate) {
    int i = blockIdx.x * 256 + threadIdx.x;
    if (i >= NN) return;
    const float4* p = (const float4*)(partial + (size_t)i * 8);
    float4 u = p[0], v = p[1];
    gate[i] = u.x + u.y + u.z + u.w + v.x + v.y + v.z + v.w + b2[0];
}

// ---------------- fused GraphNorm stats + norm + (relu) + residual, LDS row cache ----------------
__global__ __launch_bounds__(256) void k_statsnorm(const ushort* __restrict__ y, const int* __restrict__ gstart,
                                                   const float* __restrict__ alpha, const float* __restrict__ gamma,
                                                   const float* __restrict__ beta, ushort* __restrict__ x, int relu) {
    __shared__ ushort yc[LDSROWS * DIMH];   // 73728 B; column-private, no barriers needed
    int g = blockIdx.x, t = threadIdx.x;
    int s = gstart[g], e = gstart[g + 1];
    int n = e - s;
    if (n <= 0) return;
    float s1 = 0.f, s2 = 0.f;
    for (int r = 0; r < n; r++) {
        ushort raw = y[(size_t)(s + r) * DIMH + t];
        if (r < LDSROWS) yc[r * DIMH + t] = raw;
        float v = bf2f(raw);
        s1 += v; s2 = fmaf(v, v, s2);
    }
    float cnt = (float)(n > 1 ? n : 1);
    float m = s1 / cnt;
    float a = alpha[t];
    float am = a * m;
    float var = s2 / cnt - 2.f * am * m + am * am;
    float iv = rsqrtf(var + EPSV);
    float ga = gamma[t], be = beta[t];
    for (int r = 0; r < n; r++) {
        float v = (r < LDSROWS) ? bf2f(yc[r * DIMH + t]) : bf2f(y[(size_t)(s + r) * DIMH + t]);
        float xo = bf2f(x[(size_t)(s + r) * DIMH + t]);
        float o = (v - am) * iv * ga + be;
        if (relu) o = fmaxf(o, 0.f);
        x[(size_t)(s + r) * DIMH + t] = f2bf(xo + o);
    }
}

// ---------------- segment softmax + weighted pool ----------------
__global__ __launch_bounds__(256) void k_pool(const ushort* __restrict__ x, const float* __restrict__ gate,
                                              const int* __restrict__ gstart, float* __restrict__ outg) {
    __shared__ float red[256];
    __shared__ float wbuf[256];
    int g = blockIdx.x, t = threadIdx.x;
    int s = gstart[g], e = gstart[g + 1];
    if (s >= e) { outg[(size_t)g * DIMH + t] = 0.f; return; }
    float m = -3.4e38f;
    for (int i = s + t; i < e; i += 256) m = fmaxf(m, gate[i]);
    red[t] = m; __syncthreads();
    for (int o = 128; o > 0; o >>= 1) { if (t < o) red[t] = fmaxf(red[t], red[t + o]); __syncthreads(); }
    m = red[0]; __syncthreads();
    float se = 0.f;
    for (int i = s + t; i < e; i += 256) se += expf(gate[i] - m);
    red[t] = se; __syncthreads();
    for (int o = 128; o > 0; o >>= 1) { if (t < o) red[t] += red[t + o]; __syncthreads(); }
    float inv_se = 1.f / red[0];
    float o_acc = 0.f;
    for (int base = s; base < e; base += 256) {
        __syncthreads();
        int i = base + t;
        wbuf[t] = (i < e) ? expf(gate[i] - m) * inv_se : 0.f;
        __syncthreads();
        int cnt = min(256, e - base);
        for (int j = 0; j < cnt; j++) o_acc += wbuf[j] * bf2f(x[(size_t)(base + j) * DIMH + t]);
    }
    outg[(size_t)g * DIMH + t] = o_acc;
}

__global__ __launch_bounds__(256) void k_final(float* __restrict__ out) {
    const int GD = GG * DIMH;
    int i = blockIdx.x * 256 + threadIdx.x;
    if (i >= GD) return;
    float s = out[i] + out[GD + i] + out[2 * GD + i] + out[3 * GD + i];
    out[4 * GD + i] = 0.25f * s;
}

__global__ __launch_bounds__(256) void k_zero_out(float* __restrict__ out, int n) {
    int i = blockIdx.x * 256 + threadIdx.x;
    if (i < n) out[i] = 0.f;
}

// ---------------- host ----------------
extern "C" void kernel_launch(void* const* d_in, const int* in_sizes, int n_in,
                              void* d_out, int out_size, void* d_ws, size_t ws_size,
                              hipStream_t stream) {
    const int*   x_idx     = (const int*)d_in[0];
    const int*   node_dep  = (const int*)d_in[1];
    const int*   eidx      = (const int*)d_in[2];
    const int*   batch     = (const int*)d_in[3];
    const float* emb_node  = (const float*)d_in[4];
    const float* emb_depth = (const float*)d_in[5];
    const float* gin_w1    = (const float*)d_in[6];
    const float* gin_b1    = (const float*)d_in[7];
    const float* gin_w2    = (const float*)d_in[8];
    const float* gin_b2    = (const float*)d_in[9];
    const float* gn_alpha  = (const float*)d_in[10];
    const float* gn_gamma  = (const float*)d_in[11];
    const float* gn_beta   = (const float*)d_in[12];
    const float* att_w1    = (const float*)d_in[13];
    const float* att_b1    = (const float*)d_in[14];
    const float* att_w2    = (const float*)d_in[15];
    const float* att_b2    = (const float*)d_in[16];
    float* out = (float*)d_out;
    (void)in_sizes; (void)n_in;

    const size_t SZ_NODE_BF16 = (size_t)NN * DIMH * 2;      // 51.2 MB
    const size_t SZ_W256 = (size_t)NDEPTH * 256 * 256 * 2;  // 512 KB
    const size_t SZ_W512 = (size_t)NDEPTH * 256 * 512 * 2;  // 1 MB
    size_t required = 3 * ((SZ_NODE_BF16 + 255) & ~(size_t)255)
                    + 4 * SZ_W256 + 2 * SZ_W512
                    + ((size_t)EE * 4 + 256) + ((size_t)(NN + 1) * 4 + 256) * 2
                    + 4096 + 16384 + ((size_t)NN * 4 + 256) + 65536;
    if (ws_size < required) {
        k_zero_out<<<(out_size + 255) / 256, 256, 0, stream>>>(out, out_size);
        return;
    }

    char* w = (char*)d_ws;
    size_t off = 0;
    auto alloc = [&](size_t bytes) -> char* {
        char* p = w + off;
        off += (bytes + 255) & ~(size_t)255;
        return p;
    };
    ushort* x  = (ushort*)alloc(SZ_NODE_BF16);
    ushort* hb = (ushort*)alloc(SZ_NODE_BF16);   // h, then y2
    ushort* y1 = (ushort*)alloc(SZ_NODE_BF16);   // y1; aliased: ebuf (CSR build) & attgate partial
    float* partial = (float*)y1;
    int2* ebuf = (int2*)y1;                      // 12.8 MB << 51.2 MB, dead before gemm1
    ushort* wt_g1h = (ushort*)alloc(SZ_W256);
    ushort* wt_g1l = (ushort*)alloc(SZ_W256);
    ushort* wt_g2h = (ushort*)alloc(SZ_W256);
    ushort* wt_g2l = (ushort*)alloc(SZ_W256);
    ushort* wt_a1h = (ushort*)alloc(SZ_W512);
    ushort* wt_a1l = (ushort*)alloc(SZ_W512);
    int* deg    = (int*)alloc((size_t)NN * 4);   // degree, then cursor
    int* rs     = (int*)alloc((size_t)(NN + 1) * 4);
    int* part   = (int*)alloc(512 * 4);
    int* gstart = (int*)alloc((GG + 1) * 4);
    int* bcnt   = (int*)alloc((NBUCK + 1) * 4);
    int* bstart = (int*)alloc((NBUCK + 1) * 4);
    int* bcursor= (int*)alloc((NBUCK + 1) * 4);
    int* col    = (int*)alloc((size_t)EE * 4);
    float* gate = (float*)alloc((size_t)NN * 4);

    const int* src  = eidx;
    const int* dstp = eidx + EE;

    hipMemsetAsync(deg, 0, (size_t)NN * 4, stream);
    hipMemsetAsync(bcnt, 0, (NBUCK + 1) * 4, stream);
    k_graph_bounds<<<(GG + 1 + 255) / 256, 256, 0, stream>>>(batch, gstart);
    k_bhist<<<(EE + 255) / 256, 256, 0, stream>>>(dstp, bcnt);
    k_bscan<<<1, 512, 0, stream>>>(bcnt, bstart, bcursor);
    k_bscatter<<<(EE + 255) / 256, 256, 0, stream>>>(src, dstp, bcursor, ebuf, deg);
    int nb = (NN + 255) / 256;   // 391
    k_scan_a<<<nb, 256, 0, stream>>>(deg, rs, part);
    k_scan_b<<<1, 512, 0, stream>>>(part, nb, rs);
    k_scan_c<<<nb, 256, 0, stream>>>(rs, part, deg);   // deg becomes cursor
    k_scatter2<<<(EE + 255) / 256, 256, 0, stream>>>(ebuf, deg, col);
    k_encoder<<<(NN * 64 + 255) / 256, 256, 0, stream>>>(x_idx, node_dep, emb_node, emb_depth, x);

    // weight prep: transpose + hi/lo bf16 split
    k_wtrans<<<dim3(8, 8, NDEPTH), 256, 0, stream>>>(gin_w1, wt_g1h, wt_g1l, 256, 256);
    k_wtrans<<<dim3(8, 8, NDEPTH), 256, 0, stream>>>(gin_w2, wt_g2h, wt_g2l, 256, 256);
    k_wtrans<<<dim3(16, 8, NDEPTH), 256, 0, stream>>>(att_w1, wt_a1h, wt_a1l, 256, 512);

    const int GD = GG * DIMH;
    const int MB = (NN + 255) / 256;   // 391
    for (int d = 0; d < NDEPTH; d++) {
        k_aggregate<<<(NN + 3) / 4, 256, 0, stream>>>(x, rs, col, hb);
        k_gemm64<1><<<dim3(MB, 2), 256, 0, stream>>>(hb, wt_g1h + (size_t)d * 65536, wt_g1l + (size_t)d * 65536,
                                                     gin_b1 + d * 256, nullptr, y1, nullptr, NN);
        k_gemm64<0><<<dim3(MB, 2), 256, 0, stream>>>(y1, wt_g2h + (size_t)d * 65536, wt_g2l + (size_t)d * 65536,
                                                     gin_b2 + d * 256, nullptr, hb, nullptr, NN);
        k_statsnorm<<<GG, 256, 0, stream>>>(hb, gstart, gn_alpha + d * 256, gn_gamma + d * 256,
                                            gn_beta + d * 256, x, (d < NDEPTH - 1) ? 1 : 0);
        k_gemm64<2><<<dim3(MB, 4), 256, 0, stream>>>(x, wt_a1h + (size_t)d * 131072, wt_a1l + (size_t)d * 131072,
                                                     att_b1 + d * 512, att_w2 + d * 512, nullptr, partial, NN);
        k_gatefin<<<(NN + 255) / 256, 256, 0, stream>>>(partial, att_b2 + d, gate);
        k_pool<<<GG, 256, 0, stream>>>(x, gate, gstart, out + (size_t)d * GD);
    }
    k_final<<<(GD + 255) / 256, 256, 0, stream>>>(out);
}

// Round 8
// 2002.418 us; speedup vs baseline: 1.5116x; 1.5116x over previous
//
#include <hip/hip_runtime.h>
#include <hip/hip_bf16.h>

#define NN 100000
#define EE 1600000
#define GG 1000
#define DIMH 256
#define NDEPTH 4
#define LDSROWS 144        // statsnorm LDS row cache
static constexpr float EPSV = 1e-5f;

typedef unsigned short ushort;
typedef __attribute__((ext_vector_type(8))) short short8v;
typedef __attribute__((ext_vector_type(4))) float f32x4;

__device__ __forceinline__ float bf2f(ushort u) {
    return __uint_as_float(((unsigned)u) << 16);
}
__device__ __forceinline__ ushort f2bf(float f) {
    unsigned u = __float_as_uint(f);
    unsigned r = u + 0x7FFFu + ((u >> 16) & 1u);   // RNE
    return (ushort)(r >> 16);
}

#define GLOAD16(g, s) __builtin_amdgcn_global_load_lds((const __attribute__((address_space(1))) void*)(g), \
                      (__attribute__((address_space(3))) void*)(s), 16, 0, 0)

// ---------------- CSR build ----------------
__global__ __launch_bounds__(256) void k_graph_bounds(const int* __restrict__ batch, int* __restrict__ gstart) {
    int g = blockIdx.x * 256 + threadIdx.x;
    if (g > GG) return;
    int lo = 0, hi = NN;
    while (lo < hi) { int mid = (lo + hi) >> 1; if (batch[mid] < g) lo = mid + 1; else hi = mid; }
    gstart[g] = lo;
}

__global__ __launch_bounds__(256) void k_hist(const int* __restrict__ dst, int* __restrict__ deg) {
    int e = blockIdx.x * 256 + threadIdx.x;
    if (e < EE) atomicAdd(&deg[dst[e]], 1);
}

__global__ __launch_bounds__(256) void k_scan_a(const int* __restrict__ deg, int* __restrict__ rs, int* __restrict__ part) {
    __shared__ int s[256];
    int t = threadIdx.x;
    int i = blockIdx.x * 256 + t;
    int v = (i < NN) ? deg[i] : 0;
    s[t] = v; __syncthreads();
    for (int off = 1; off < 256; off <<= 1) {
        int u = (t >= off) ? s[t - off] : 0;
        __syncthreads();
        s[t] += u;
        __syncthreads();
    }
    if (i < NN) rs[i] = s[t] - v;
    if (t == 255) part[blockIdx.x] = s[255];
}

__global__ __launch_bounds__(512) void k_scan_b(int* __restrict__ part, int nb, int* __restrict__ rs) {
    __shared__ int s[512];
    int t = threadIdx.x;
    int v = (t < nb) ? part[t] : 0;
    s[t] = v; __syncthreads();
    for (int off = 1; off < 512; off <<= 1) {
        int u = (t >= off) ? s[t - off] : 0;
        __syncthreads();
        s[t] += u;
        __syncthreads();
    }
    if (t < nb) part[t] = s[t] - v;  // exclusive
    if (t == 0) rs[NN] = EE;
}

// finalize row starts AND copy to cursor
__global__ __launch_bounds__(256) void k_scan_c(int* __restrict__ rs, const int* __restrict__ part,
                                                int* __restrict__ cursor) {
    int i = blockIdx.x * 256 + threadIdx.x;
    if (i < NN) {
        int v = rs[i] + part[blockIdx.x];
        rs[i] = v;
        cursor[i] = v;
    }
}

__global__ __launch_bounds__(256) void k_scatter(const int* __restrict__ src, const int* __restrict__ dst,
                                                 int* __restrict__ cursor, int* __restrict__ col) {
    int e = blockIdx.x * 256 + threadIdx.x;
    if (e >= EE) return;
    int d = dst[e];
    int pos = atomicAdd(&cursor[d], 1);
    col[pos] = src[e];
}

// ---------------- weight transpose + bf16 split: W[K][N] f32 -> Wt_hi/lo[N][K] bf16 ----------------
__global__ __launch_bounds__(256) void k_wtrans(const float* __restrict__ in, ushort* __restrict__ out_hi,
                                                ushort* __restrict__ out_lo, int K, int N) {
    int d = blockIdx.z;
    in  += (size_t)d * K * N;
    out_hi += (size_t)d * K * N;
    out_lo += (size_t)d * K * N;
    int n0 = blockIdx.x * 32, k0 = blockIdx.y * 32;
    int t = threadIdx.x;
    int tx = t & 31, ty = t >> 5;      // ty 0..7
    __shared__ float tile[32][33];
#pragma unroll
    for (int j = 0; j < 4; j++) tile[ty + 8 * j][tx] = in[(size_t)(k0 + ty + 8 * j) * N + n0 + tx];
    __syncthreads();
#pragma unroll
    for (int j = 0; j < 4; j++) {
        float f = tile[tx][ty + 8 * j];
        ushort hi = f2bf(f);
        float lo = f - bf2f(hi);
        size_t o = (size_t)(n0 + ty + 8 * j) * K + k0 + tx;
        out_hi[o] = hi;
        out_lo[o] = f2bf(lo);
    }
}

// ---------------- node encoder ----------------
__global__ __launch_bounds__(256) void k_encoder(const int* __restrict__ xidx, const int* __restrict__ ndep,
                                                 const float* __restrict__ en, const float* __restrict__ ed,
                                                 ushort* __restrict__ x) {
    int gi = blockIdx.x * 256 + threadIdx.x;     // = node*64 + q
    int node = gi >> 6, q = gi & 63;
    if (node >= NN) return;
    float4 va = ((const float4*)en)[(size_t)xidx[node] * 64 + q];
    float4 vb = ((const float4*)ed)[(size_t)ndep[node] * 64 + q];
    ushort4 o;
    o.x = f2bf(va.x + vb.x); o.y = f2bf(va.y + vb.y);
    o.z = f2bf(va.z + vb.z); o.w = f2bf(va.w + vb.w);
    ((ushort4*)x)[gi] = o;
}

// ---------------- GIN aggregate (8 gathers in flight, 4 accumulator chains) ----------------
__global__ __launch_bounds__(256) void k_aggregate(const ushort* __restrict__ x, const int* __restrict__ rs,
                                                   const int* __restrict__ col, ushort* __restrict__ hb) {
    int node = blockIdx.x * 4 + (threadIdx.x >> 6);
    int lane = threadIdx.x & 63;
    if (node >= NN) return;
    const ushort4* x4 = (const ushort4*)x;
    ushort4 sv = x4[(size_t)node * 64 + lane];
    float a0 = bf2f(sv.x), a1 = bf2f(sv.y), a2 = bf2f(sv.z), a3 = bf2f(sv.w);
    float b0 = 0.f, b1 = 0.f, b2 = 0.f, b3 = 0.f;
    float c0 = 0.f, c1 = 0.f, c2 = 0.f, c3 = 0.f;
    float d0 = 0.f, d1 = 0.f, d2 = 0.f, d3 = 0.f;
    int s = rs[node], e = rs[node + 1];
    int j = s;
    for (; j + 8 <= e; j += 8) {
        int i0 = col[j], i1 = col[j + 1], i2 = col[j + 2], i3 = col[j + 3];
        int i4 = col[j + 4], i5 = col[j + 5], i6 = col[j + 6], i7 = col[j + 7];
        ushort4 v0 = x4[(size_t)i0 * 64 + lane];
        ushort4 v1 = x4[(size_t)i1 * 64 + lane];
        ushort4 v2 = x4[(size_t)i2 * 64 + lane];
        ushort4 v3 = x4[(size_t)i3 * 64 + lane];
        ushort4 v4 = x4[(size_t)i4 * 64 + lane];
        ushort4 v5 = x4[(size_t)i5 * 64 + lane];
        ushort4 v6 = x4[(size_t)i6 * 64 + lane];
        ushort4 v7 = x4[(size_t)i7 * 64 + lane];
        a0 += bf2f(v0.x); a1 += bf2f(v0.y); a2 += bf2f(v0.z); a3 += bf2f(v0.w);
        b0 += bf2f(v1.x); b1 += bf2f(v1.y); b2 += bf2f(v1.z); b3 += bf2f(v1.w);
        c0 += bf2f(v2.x); c1 += bf2f(v2.y); c2 += bf2f(v2.z); c3 += bf2f(v2.w);
        d0 += bf2f(v3.x); d1 += bf2f(v3.y); d2 += bf2f(v3.z); d3 += bf2f(v3.w);
        a0 += bf2f(v4.x); a1 += bf2f(v4.y); a2 += bf2f(v4.z); a3 += bf2f(v4.w);
        b0 += bf2f(v5.x); b1 += bf2f(v5.y); b2 += bf2f(v5.z); b3 += bf2f(v5.w);
        c0 += bf2f(v6.x); c1 += bf2f(v6.y); c2 += bf2f(v6.z); c3 += bf2f(v6.w);
        d0 += bf2f(v7.x); d1 += bf2f(v7.y); d2 += bf2f(v7.z); d3 += bf2f(v7.w);
    }
    for (; j + 4 <= e; j += 4) {
        int i0 = col[j], i1 = col[j + 1], i2 = col[j + 2], i3 = col[j + 3];
        ushort4 v0 = x4[(size_t)i0 * 64 + lane];
        ushort4 v1 = x4[(size_t)i1 * 64 + lane];
        ushort4 v2 = x4[(size_t)i2 * 64 + lane];
        ushort4 v3 = x4[(size_t)i3 * 64 + lane];
        a0 += bf2f(v0.x); a1 += bf2f(v0.y); a2 += bf2f(v0.z); a3 += bf2f(v0.w);
        b0 += bf2f(v1.x); b1 += bf2f(v1.y); b2 += bf2f(v1.z); b3 += bf2f(v1.w);
        c0 += bf2f(v2.x); c1 += bf2f(v2.y); c2 += bf2f(v2.z); c3 += bf2f(v2.w);
        d0 += bf2f(v3.x); d1 += bf2f(v3.y); d2 += bf2f(v3.z); d3 += bf2f(v3.w);
    }
    for (; j < e; j++) {
        int c = col[j];
        ushort4 v = x4[(size_t)c * 64 + lane];
        a0 += bf2f(v.x); a1 += bf2f(v.y); a2 += bf2f(v.z); a3 += bf2f(v.w);
    }
    a0 += b0 + c0 + d0; a1 += b1 + c1 + d1; a2 += b2 + c2 + d2; a3 += b3 + c3 + d3;
    ushort4 o; o.x = f2bf(a0); o.y = f2bf(a1); o.z = f2bf(a2); o.w = f2bf(a3);
    ((ushort4*)hb)[(size_t)node * 64 + lane] = o;
}

// ============ GEMM v4: block 256x128, 4 waves of 128x64, K_STEP=64, stage->barrier->compute ============
// MODE 0: bias, store bf16.  MODE 1: bias+relu, store bf16.  MODE 2: attgate partial -> partial[row][by*2+wc]
template<int MODE>
__global__ __launch_bounds__(256, 2) void k_gemm64(const ushort* __restrict__ A,
                                                   const ushort* __restrict__ Bhi,
                                                   const ushort* __restrict__ Blo,
                                                   const float* __restrict__ bias,
                                                   const float* __restrict__ w2,
                                                   ushort* __restrict__ C,
                                                   float* __restrict__ partial,
                                                   int M) {
    __shared__ __align__(16) ushort As[256 * 64];   // 32 KB
    __shared__ __align__(16) ushort Bh[128 * 64];   // 16 KB
    __shared__ __align__(16) ushort Bl[128 * 64];   // 16 KB
    int t = threadIdx.x;
    int wv = t >> 6, l = t & 63;
    int wr = wv >> 1, wc = wv & 1;
    int row0 = blockIdx.x * 256;
    int col0 = blockIdx.y * 128;

    f32x4 acc[8][4];
#pragma unroll
    for (int m = 0; m < 8; m++)
#pragma unroll
        for (int n = 0; n < 4; n++) acc[m][n] = (f32x4){0.f, 0.f, 0.f, 0.f};

    int srow_in = l >> 3;       // 0..7
    int slot    = l & 7;        // 16B chunk slot within a 128B row

    for (int k0 = 0; k0 < 256; k0 += 64) {
#pragma unroll
        for (int i = 0; i < 8; i++) {
            int stripe = wv * 8 + i;                // 0..31
            int rl = stripe * 8 + srow_in;          // 0..255
            int gc = slot ^ (rl & 7);               // pre-swizzled global chunk
            const ushort* ga = A + (size_t)min(row0 + rl, M - 1) * 256 + k0 + gc * 8;
            GLOAD16(ga, As + stripe * 512 + l * 8);
        }
#pragma unroll
        for (int i = 0; i < 4; i++) {
            int stripe = wv * 4 + i;                // 0..15
            int rl = stripe * 8 + srow_in;          // 0..127
            int gc = slot ^ (rl & 7);
            const ushort* gh = Bhi + (size_t)(col0 + rl) * 256 + k0 + gc * 8;
            GLOAD16(gh, Bh + stripe * 512 + l * 8);
            const ushort* gl = Blo + (size_t)(col0 + rl) * 256 + k0 + gc * 8;
            GLOAD16(gl, Bl + stripe * 512 + l * 8);
        }
        __syncthreads();
#pragma unroll
        for (int s = 0; s < 2; s++) {
            short8v af[8], bhf[4], blf[4];
#pragma unroll
            for (int m = 0; m < 8; m++) {
                int r = wr * 128 + m * 16 + (l & 15);
                int ch = (s * 4 + (l >> 4)) ^ (r & 7);
                af[m] = *(const short8v*)(As + r * 64 + ch * 8);
            }
#pragma unroll
            for (int n = 0; n < 4; n++) {
                int rb = wc * 64 + n * 16 + (l & 15);
                int ch = (s * 4 + (l >> 4)) ^ (rb & 7);
                bhf[n] = *(const short8v*)(Bh + rb * 64 + ch * 8);
                blf[n] = *(const short8v*)(Bl + rb * 64 + ch * 8);
            }
#pragma unroll
            for (int m = 0; m < 8; m++)
#pragma unroll
                for (int n = 0; n < 4; n++) {
                    acc[m][n] = __builtin_amdgcn_mfma_f32_16x16x32_bf16(af[m], bhf[n], acc[m][n], 0, 0, 0);
                    acc[m][n] = __builtin_amdgcn_mfma_f32_16x16x32_bf16(af[m], blf[n], acc[m][n], 0, 0, 0);
                }
        }
        __syncthreads();
    }

    int lr = l & 15, kc = l >> 4;
    if (MODE == 2) {
        float b1v[4], w2v[4];
#pragma unroll
        for (int n = 0; n < 4; n++) {
            int colc = col0 + wc * 64 + n * 16 + lr;
            b1v[n] = bias[colc];
            w2v[n] = w2[colc];
        }
#pragma unroll
        for (int m = 0; m < 8; m++) {
#pragma unroll
            for (int j = 0; j < 4; j++) {
                float p = 0.f;
#pragma unroll
                for (int n = 0; n < 4; n++) {
                    float v = fmaxf(acc[m][n][j] + b1v[n], 0.f);
                    p = fmaf(v, w2v[n], p);
                }
#pragma unroll
                for (int off = 1; off < 16; off <<= 1) p += __shfl_xor(p, off, 64);
                if (lr == 0) {
                    int row = row0 + wr * 128 + m * 16 + (kc << 2) + j;
                    if (row < M) partial[(size_t)row * 8 + blockIdx.y * 2 + wc] = p;
                }
            }
        }
    } else {
        float bv[4];
#pragma unroll
        for (int n = 0; n < 4; n++) bv[n] = bias[col0 + wc * 64 + n * 16 + lr];
#pragma unroll
        for (int m = 0; m < 8; m++) {
#pragma unroll
            for (int j = 0; j < 4; j++) {
                int row = row0 + wr * 128 + m * 16 + (kc << 2) + j;
                if (row < M) {
#pragma unroll
                    for (int n = 0; n < 4; n++) {
                        float v = acc[m][n][j] + bv[n];
                        if (MODE == 1) v = fmaxf(v, 0.f);
                        C[(size_t)row * 256 + col0 + wc * 64 + n * 16 + lr] = f2bf(v);
                    }
                }
            }
        }
    }
}

// ---------------- gate finisher ----------------
__global__ __launch_bounds__(256) void k_gatefin(const float* __restrict__ partial, const float* __restrict__ b2,
                                                 float* __restrict__ gate) {
    int i = blockIdx.x * 256 + threadIdx.x;
    if (i >= NN) return;
    const float4* p = (const float4*)(partial + (size_t)i * 8);
    float4 u = p[0], v = p[1];
    gate[i] = u.x + u.y + u.z + u.w + v.x + v.y + v.z + v.w + b2[0];
}

// ---------------- fused GraphNorm stats + norm + (relu) + residual, LDS row cache ----------------
__global__ __launch_bounds__(256) void k_statsnorm(const ushort* __restrict__ y, const int* __restrict__ gstart,
                                                   const float* __restrict__ alpha, const float* __restrict__ gamma,
                                                   const float* __restrict__ beta, ushort* __restrict__ x, int relu) {
    __shared__ ushort yc[LDSROWS * DIMH];   // 73728 B; column-private, no barriers needed
    int g = blockIdx.x, t = threadIdx.x;
    int s = gstart[g], e = gstart[g + 1];
    int n = e - s;
    if (n <= 0) return;
    float s1 = 0.f, s2 = 0.f;
    for (int r = 0; r < n; r++) {
        ushort raw = y[(size_t)(s + r) * DIMH + t];
        if (r < LDSROWS) yc[r * DIMH + t] = raw;
        float v = bf2f(raw);
        s1 += v; s2 = fmaf(v, v, s2);
    }
    float cnt = (float)(n > 1 ? n : 1);
    float m = s1 / cnt;
    float a = alpha[t];
    float am = a * m;
    float var = s2 / cnt - 2.f * am * m + am * am;
    float iv = rsqrtf(var + EPSV);
    float ga = gamma[t], be = beta[t];
    for (int r = 0; r < n; r++) {
        float v = (r < LDSROWS) ? bf2f(yc[r * DIMH + t]) : bf2f(y[(size_t)(s + r) * DIMH + t]);
        float xo = bf2f(x[(size_t)(s + r) * DIMH + t]);
        float o = (v - am) * iv * ga + be;
        if (relu) o = fmaxf(o, 0.f);
        x[(size_t)(s + r) * DIMH + t] = f2bf(xo + o);
    }
}

// ---------------- segment softmax + weighted pool ----------------
__global__ __launch_bounds__(256) void k_pool(const ushort* __restrict__ x, const float* __restrict__ gate,
                                              const int* __restrict__ gstart, float* __restrict__ outg) {
    __shared__ float red[256];
    __shared__ float wbuf[256];
    int g = blockIdx.x, t = threadIdx.x;
    int s = gstart[g], e = gstart[g + 1];
    if (s >= e) { outg[(size_t)g * DIMH + t] = 0.f; return; }
    float m = -3.4e38f;
    for (int i = s + t; i < e; i += 256) m = fmaxf(m, gate[i]);
    red[t] = m; __syncthreads();
    for (int o = 128; o > 0; o >>= 1) { if (t < o) red[t] = fmaxf(red[t], red[t + o]); __syncthreads(); }
    m = red[0]; __syncthreads();
    float se = 0.f;
    for (int i = s + t; i < e; i += 256) se += expf(gate[i] - m);
    red[t] = se; __syncthreads();
    for (int o = 128; o > 0; o >>= 1) { if (t < o) red[t] += red[t + o]; __syncthreads(); }
    float inv_se = 1.f / red[0];
    float o_acc = 0.f;
    for (int base = s; base < e; base += 256) {
        __syncthreads();
        int i = base + t;
        wbuf[t] = (i < e) ? expf(gate[i] - m) * inv_se : 0.f;
        __syncthreads();
        int cnt = min(256, e - base);
        for (int j = 0; j < cnt; j++) o_acc += wbuf[j] * bf2f(x[(size_t)(base + j) * DIMH + t]);
    }
    outg[(size_t)g * DIMH + t] = o_acc;
}

__global__ __launch_bounds__(256) void k_final(float* __restrict__ out) {
    const int GD = GG * DIMH;
    int i = blockIdx.x * 256 + threadIdx.x;
    if (i >= GD) return;
    float s = out[i] + out[GD + i] + out[2 * GD + i] + out[3 * GD + i];
    out[4 * GD + i] = 0.25f * s;
}

__global__ __launch_bounds__(256) void k_zero_out(float* __restrict__ out, int n) {
    int i = blockIdx.x * 256 + threadIdx.x;
    if (i < n) out[i] = 0.f;
}

// ---------------- host ----------------
extern "C" void kernel_launch(void* const* d_in, const int* in_sizes, int n_in,
                              void* d_out, int out_size, void* d_ws, size_t ws_size,
                              hipStream_t stream) {
    const int*   x_idx     = (const int*)d_in[0];
    const int*   node_dep  = (const int*)d_in[1];
    const int*   eidx      = (const int*)d_in[2];
    const int*   batch     = (const int*)d_in[3];
    const float* emb_node  = (const float*)d_in[4];
    const float* emb_depth = (const float*)d_in[5];
    const float* gin_w1    = (const float*)d_in[6];
    const float* gin_b1    = (const float*)d_in[7];
    const float* gin_w2    = (const float*)d_in[8];
    const float* gin_b2    = (const float*)d_in[9];
    const float* gn_alpha  = (const float*)d_in[10];
    const float* gn_gamma  = (const float*)d_in[11];
    const float* gn_beta   = (const float*)d_in[12];
    const float* att_w1    = (const float*)d_in[13];
    const float* att_b1    = (const float*)d_in[14];
    const float* att_w2    = (const float*)d_in[15];
    const float* att_b2    = (const float*)d_in[16];
    float* out = (float*)d_out;
    (void)in_sizes; (void)n_in;

    const size_t SZ_NODE_BF16 = (size_t)NN * DIMH * 2;      // 51.2 MB
    const size_t SZ_W256 = (size_t)NDEPTH * 256 * 256 * 2;  // 512 KB
    const size_t SZ_W512 = (size_t)NDEPTH * 256 * 512 * 2;  // 1 MB
    size_t required = 3 * ((SZ_NODE_BF16 + 255) & ~(size_t)255)
                    + 4 * SZ_W256 + 2 * SZ_W512
                    + ((size_t)EE * 4 + 256) + ((size_t)(NN + 1) * 4 + 256) * 2
                    + 4096 + 8192 + ((size_t)NN * 4 + 256) + 65536;
    if (ws_size < required) {
        k_zero_out<<<(out_size + 255) / 256, 256, 0, stream>>>(out, out_size);
        return;
    }

    char* w = (char*)d_ws;
    size_t off = 0;
    auto alloc = [&](size_t bytes) -> char* {
        char* p = w + off;
        off += (bytes + 255) & ~(size_t)255;
        return p;
    };
    ushort* x  = (ushort*)alloc(SZ_NODE_BF16);
    ushort* hb = (ushort*)alloc(SZ_NODE_BF16);   // h, then y2
    ushort* y1 = (ushort*)alloc(SZ_NODE_BF16);   // y1; reused as attgate partial f32 [N][8]
    float* partial = (float*)y1;
    ushort* wt_g1h = (ushort*)alloc(SZ_W256);
    ushort* wt_g1l = (ushort*)alloc(SZ_W256);
    ushort* wt_g2h = (ushort*)alloc(SZ_W256);
    ushort* wt_g2l = (ushort*)alloc(SZ_W256);
    ushort* wt_a1h = (ushort*)alloc(SZ_W512);
    ushort* wt_a1l = (ushort*)alloc(SZ_W512);
    int* deg    = (int*)alloc((size_t)NN * 4);   // degree, then cursor
    int* rs     = (int*)alloc((size_t)(NN + 1) * 4);
    int* part   = (int*)alloc(512 * 4);
    int* gstart = (int*)alloc((GG + 1) * 4);
    int* col    = (int*)alloc((size_t)EE * 4);
    float* gate = (float*)alloc((size_t)NN * 4);

    const int* src  = eidx;
    const int* dstp = eidx + EE;

    hipMemsetAsync(deg, 0, (size_t)NN * 4, stream);
    k_graph_bounds<<<(GG + 1 + 255) / 256, 256, 0, stream>>>(batch, gstart);
    k_hist<<<(EE + 255) / 256, 256, 0, stream>>>(dstp, deg);
    int nb = (NN + 255) / 256;   // 391
    k_scan_a<<<nb, 256, 0, stream>>>(deg, rs, part);
    k_scan_b<<<1, 512, 0, stream>>>(part, nb, rs);
    k_scan_c<<<nb, 256, 0, stream>>>(rs, part, deg);   // deg becomes cursor
    k_scatter<<<(EE + 255) / 256, 256, 0, stream>>>(src, dstp, deg, col);
    k_encoder<<<(NN * 64 + 255) / 256, 256, 0, stream>>>(x_idx, node_dep, emb_node, emb_depth, x);

    // weight prep: transpose + hi/lo bf16 split
    k_wtrans<<<dim3(8, 8, NDEPTH), 256, 0, stream>>>(gin_w1, wt_g1h, wt_g1l, 256, 256);
    k_wtrans<<<dim3(8, 8, NDEPTH), 256, 0, stream>>>(gin_w2, wt_g2h, wt_g2l, 256, 256);
    k_wtrans<<<dim3(16, 8, NDEPTH), 256, 0, stream>>>(att_w1, wt_a1h, wt_a1l, 256, 512);

    const int GD = GG * DIMH;
    const int MB = (NN + 255) / 256;   // 391
    for (int d = 0; d < NDEPTH; d++) {
        k_aggregate<<<(NN + 3) / 4, 256, 0, stream>>>(x, rs, col, hb);
        k_gemm64<1><<<dim3(MB, 2), 256, 0, stream>>>(hb, wt_g1h + (size_t)d * 65536, wt_g1l + (size_t)d * 65536,
                                                     gin_b1 + d * 256, nullptr, y1, nullptr, NN);
        k_gemm64<0><<<dim3(MB, 2), 256, 0, stream>>>(y1, wt_g2h + (size_t)d * 65536, wt_g2l + (size_t)d * 65536,
                                                     gin_b2 + d * 256, nullptr, hb, nullptr, NN);
        k_statsnorm<<<GG, 256, 0, stream>>>(hb, gstart, gn_alpha + d * 256, gn_gamma + d * 256,
                                            gn_beta + d * 256, x, (d < NDEPTH - 1) ? 1 : 0);
        k_gemm64<2><<<dim3(MB, 4), 256, 0, stream>>>(x, wt_a1h + (size_t)d * 131072, wt_a1l + (size_t)d * 131072,
                                                     att_b1 + d * 512, att_w2 + d * 512, nullptr, partial, NN);
        k_gatefin<<<(NN + 255) / 256, 256, 0, stream>>>(partial, att_b2 + d, gate);
        k_pool<<<GG, 256, 0, stream>>>(x, gate, gstart, out + (size_t)d * GD);
    }
    k_final<<<(GD + 255) / 256, 256, 0, stream>>>(out);
}

// Round 9
// 1609.676 us; speedup vs baseline: 1.8805x; 1.2440x over previous
//
#include <hip/hip_runtime.h>
#include <hip/hip_bf16.h>

#define NN 100000
#define EE 1600000
#define GG 1000
#define DIMH 256
#define NDEPTH 4
static constexpr float EPSV = 1e-5f;

typedef unsigned short ushort;
typedef __attribute__((ext_vector_type(8))) short short8v;
typedef __attribute__((ext_vector_type(4))) float f32x4;

__device__ __forceinline__ float bf2f(ushort u) {
    return __uint_as_float(((unsigned)u) << 16);
}
__device__ __forceinline__ ushort f2bf(float f) {
    unsigned u = __float_as_uint(f);
    unsigned r = u + 0x7FFFu + ((u >> 16) & 1u);   // RNE
    return (ushort)(r >> 16);
}

#define GLOAD16(g, s) __builtin_amdgcn_global_load_lds((const __attribute__((address_space(1))) void*)(g), \
                      (__attribute__((address_space(3))) void*)(s), 16, 0, 0)

// ---------------- CSR build ----------------
__global__ __launch_bounds__(256) void k_graph_bounds(const int* __restrict__ batch, int* __restrict__ gstart) {
    int g = blockIdx.x * 256 + threadIdx.x;
    if (g > GG) return;
    int lo = 0, hi = NN;
    while (lo < hi) { int mid = (lo + hi) >> 1; if (batch[mid] < g) lo = mid + 1; else hi = mid; }
    gstart[g] = lo;
}

__global__ __launch_bounds__(256) void k_hist(const int* __restrict__ dst, int* __restrict__ deg) {
    int e = blockIdx.x * 256 + threadIdx.x;
    if (e < EE) atomicAdd(&deg[dst[e]], 1);
}

__global__ __launch_bounds__(256) void k_scan_a(const int* __restrict__ deg, int* __restrict__ rs, int* __restrict__ part) {
    __shared__ int s[256];
    int t = threadIdx.x;
    int i = blockIdx.x * 256 + t;
    int v = (i < NN) ? deg[i] : 0;
    s[t] = v; __syncthreads();
    for (int off = 1; off < 256; off <<= 1) {
        int u = (t >= off) ? s[t - off] : 0;
        __syncthreads();
        s[t] += u;
        __syncthreads();
    }
    if (i < NN) rs[i] = s[t] - v;
    if (t == 255) part[blockIdx.x] = s[255];
}

__global__ __launch_bounds__(512) void k_scan_b(int* __restrict__ part, int nb, int* __restrict__ rs) {
    __shared__ int s[512];
    int t = threadIdx.x;
    int v = (t < nb) ? part[t] : 0;
    s[t] = v; __syncthreads();
    for (int off = 1; off < 512; off <<= 1) {
        int u = (t >= off) ? s[t - off] : 0;
        __syncthreads();
        s[t] += u;
        __syncthreads();
    }
    if (t < nb) part[t] = s[t] - v;  // exclusive
    if (t == 0) rs[NN] = EE;
}

// finalize row starts AND copy to cursor
__global__ __launch_bounds__(256) void k_scan_c(int* __restrict__ rs, const int* __restrict__ part,
                                                int* __restrict__ cursor) {
    int i = blockIdx.x * 256 + threadIdx.x;
    if (i < NN) {
        int v = rs[i] + part[blockIdx.x];
        rs[i] = v;
        cursor[i] = v;
    }
}

__global__ __launch_bounds__(256) void k_scatter(const int* __restrict__ src, const int* __restrict__ dst,
                                                 int* __restrict__ cursor, int* __restrict__ col) {
    int e = blockIdx.x * 256 + threadIdx.x;
    if (e >= EE) return;
    int d = dst[e];
    int pos = atomicAdd(&cursor[d], 1);
    col[pos] = src[e];
}

// ---------------- weight transpose + bf16 split: W[K][N] f32 -> Wt_hi/lo[N][K] bf16 ----------------
__global__ __launch_bounds__(256) void k_wtrans(const float* __restrict__ in, ushort* __restrict__ out_hi,
                                                ushort* __restrict__ out_lo, int K, int N) {
    int d = blockIdx.z;
    in  += (size_t)d * K * N;
    out_hi += (size_t)d * K * N;
    out_lo += (size_t)d * K * N;
    int n0 = blockIdx.x * 32, k0 = blockIdx.y * 32;
    int t = threadIdx.x;
    int tx = t & 31, ty = t >> 5;      // ty 0..7
    __shared__ float tile[32][33];
#pragma unroll
    for (int j = 0; j < 4; j++) tile[ty + 8 * j][tx] = in[(size_t)(k0 + ty + 8 * j) * N + n0 + tx];
    __syncthreads();
#pragma unroll
    for (int j = 0; j < 4; j++) {
        float f = tile[tx][ty + 8 * j];
        ushort hi = f2bf(f);
        float lo = f - bf2f(hi);
        size_t o = (size_t)(n0 + ty + 8 * j) * K + k0 + tx;
        out_hi[o] = hi;
        out_lo[o] = f2bf(lo);
    }
}

// ---------------- node encoder ----------------
__global__ __launch_bounds__(256) void k_encoder(const int* __restrict__ xidx, const int* __restrict__ ndep,
                                                 const float* __restrict__ en, const float* __restrict__ ed,
                                                 ushort* __restrict__ x) {
    int gi = blockIdx.x * 256 + threadIdx.x;     // = node*64 + q
    int node = gi >> 6, q = gi & 63;
    if (node >= NN) return;
    float4 va = ((const float4*)en)[(size_t)xidx[node] * 64 + q];
    float4 vb = ((const float4*)ed)[(size_t)ndep[node] * 64 + q];
    ushort4 o;
    o.x = f2bf(va.x + vb.x); o.y = f2bf(va.y + vb.y);
    o.z = f2bf(va.z + vb.z); o.w = f2bf(va.w + vb.w);
    ((ushort4*)x)[gi] = o;
}

// ---------------- GIN aggregate (8 gathers in flight, 4 accumulator chains) ----------------
__global__ __launch_bounds__(256) void k_aggregate(const ushort* __restrict__ x, const int* __restrict__ rs,
                                                   const int* __restrict__ col, ushort* __restrict__ hb) {
    int node = blockIdx.x * 4 + (threadIdx.x >> 6);
    int lane = threadIdx.x & 63;
    if (node >= NN) return;
    const ushort4* x4 = (const ushort4*)x;
    ushort4 sv = x4[(size_t)node * 64 + lane];
    float a0 = bf2f(sv.x), a1 = bf2f(sv.y), a2 = bf2f(sv.z), a3 = bf2f(sv.w);
    float b0 = 0.f, b1 = 0.f, b2 = 0.f, b3 = 0.f;
    float c0 = 0.f, c1 = 0.f, c2 = 0.f, c3 = 0.f;
    float d0 = 0.f, d1 = 0.f, d2 = 0.f, d3 = 0.f;
    int s = rs[node], e = rs[node + 1];
    int j = s;
    for (; j + 8 <= e; j += 8) {
        int i0 = col[j], i1 = col[j + 1], i2 = col[j + 2], i3 = col[j + 3];
        int i4 = col[j + 4], i5 = col[j + 5], i6 = col[j + 6], i7 = col[j + 7];
        ushort4 v0 = x4[(size_t)i0 * 64 + lane];
        ushort4 v1 = x4[(size_t)i1 * 64 + lane];
        ushort4 v2 = x4[(size_t)i2 * 64 + lane];
        ushort4 v3 = x4[(size_t)i3 * 64 + lane];
        ushort4 v4 = x4[(size_t)i4 * 64 + lane];
        ushort4 v5 = x4[(size_t)i5 * 64 + lane];
        ushort4 v6 = x4[(size_t)i6 * 64 + lane];
        ushort4 v7 = x4[(size_t)i7 * 64 + lane];
        a0 += bf2f(v0.x); a1 += bf2f(v0.y); a2 += bf2f(v0.z); a3 += bf2f(v0.w);
        b0 += bf2f(v1.x); b1 += bf2f(v1.y); b2 += bf2f(v1.z); b3 += bf2f(v1.w);
        c0 += bf2f(v2.x); c1 += bf2f(v2.y); c2 += bf2f(v2.z); c3 += bf2f(v2.w);
        d0 += bf2f(v3.x); d1 += bf2f(v3.y); d2 += bf2f(v3.z); d3 += bf2f(v3.w);
        a0 += bf2f(v4.x); a1 += bf2f(v4.y); a2 += bf2f(v4.z); a3 += bf2f(v4.w);
        b0 += bf2f(v5.x); b1 += bf2f(v5.y); b2 += bf2f(v5.z); b3 += bf2f(v5.w);
        c0 += bf2f(v6.x); c1 += bf2f(v6.y); c2 += bf2f(v6.z); c3 += bf2f(v6.w);
        d0 += bf2f(v7.x); d1 += bf2f(v7.y); d2 += bf2f(v7.z); d3 += bf2f(v7.w);
    }
    for (; j + 4 <= e; j += 4) {
        int i0 = col[j], i1 = col[j + 1], i2 = col[j + 2], i3 = col[j + 3];
        ushort4 v0 = x4[(size_t)i0 * 64 + lane];
        ushort4 v1 = x4[(size_t)i1 * 64 + lane];
        ushort4 v2 = x4[(size_t)i2 * 64 + lane];
        ushort4 v3 = x4[(size_t)i3 * 64 + lane];
        a0 += bf2f(v0.x); a1 += bf2f(v0.y); a2 += bf2f(v0.z); a3 += bf2f(v0.w);
        b0 += bf2f(v1.x); b1 += bf2f(v1.y); b2 += bf2f(v1.z); b3 += bf2f(v1.w);
        c0 += bf2f(v2.x); c1 += bf2f(v2.y); c2 += bf2f(v2.z); c3 += bf2f(v2.w);
        d0 += bf2f(v3.x); d1 += bf2f(v3.y); d2 += bf2f(v3.z); d3 += bf2f(v3.w);
    }
    for (; j < e; j++) {
        int c = col[j];
        ushort4 v = x4[(size_t)c * 64 + lane];
        a0 += bf2f(v.x); a1 += bf2f(v.y); a2 += bf2f(v.z); a3 += bf2f(v.w);
    }
    a0 += b0 + c0 + d0; a1 += b1 + c1 + d1; a2 += b2 + c2 + d2; a3 += b3 + c3 + d3;
    ushort4 o; o.x = f2bf(a0); o.y = f2bf(a1); o.z = f2bf(a2); o.w = f2bf(a3);
    ((ushort4*)hb)[(size_t)node * 64 + lane] = o;
}

// ============ GEMM v4: block 256x128, 4 waves of 128x64, K_STEP=64, stage->barrier->compute ============
// MODE 0: bias, store bf16.  MODE 1: bias+relu, store bf16.  MODE 2: attgate partial -> partial[row][by*2+wc]
template<int MODE>
__global__ __launch_bounds__(256, 2) void k_gemm64(const ushort* __restrict__ A,
                                                   const ushort* __restrict__ Bhi,
                                                   const ushort* __restrict__ Blo,
                                                   const float* __restrict__ bias,
                                                   const float* __restrict__ w2,
                                                   ushort* __restrict__ C,
                                                   float* __restrict__ partial,
                                                   int M) {
    __shared__ __align__(16) ushort As[256 * 64];   // 32 KB
    __shared__ __align__(16) ushort Bh[128 * 64];   // 16 KB
    __shared__ __align__(16) ushort Bl[128 * 64];   // 16 KB
    int t = threadIdx.x;
    int wv = t >> 6, l = t & 63;
    int wr = wv >> 1, wc = wv & 1;
    int row0 = blockIdx.x * 256;
    int col0 = blockIdx.y * 128;

    f32x4 acc[8][4];
#pragma unroll
    for (int m = 0; m < 8; m++)
#pragma unroll
        for (int n = 0; n < 4; n++) acc[m][n] = (f32x4){0.f, 0.f, 0.f, 0.f};

    int srow_in = l >> 3;       // 0..7
    int slot    = l & 7;        // 16B chunk slot within a 128B row

    for (int k0 = 0; k0 < 256; k0 += 64) {
#pragma unroll
        for (int i = 0; i < 8; i++) {
            int stripe = wv * 8 + i;                // 0..31
            int rl = stripe * 8 + srow_in;          // 0..255
            int gc = slot ^ (rl & 7);               // pre-swizzled global chunk
            const ushort* ga = A + (size_t)min(row0 + rl, M - 1) * 256 + k0 + gc * 8;
            GLOAD16(ga, As + stripe * 512 + l * 8);
        }
#pragma unroll
        for (int i = 0; i < 4; i++) {
            int stripe = wv * 4 + i;                // 0..15
            int rl = stripe * 8 + srow_in;          // 0..127
            int gc = slot ^ (rl & 7);
            const ushort* gh = Bhi + (size_t)(col0 + rl) * 256 + k0 + gc * 8;
            GLOAD16(gh, Bh + stripe * 512 + l * 8);
            const ushort* gl = Blo + (size_t)(col0 + rl) * 256 + k0 + gc * 8;
            GLOAD16(gl, Bl + stripe * 512 + l * 8);
        }
        __syncthreads();
#pragma unroll
        for (int s = 0; s < 2; s++) {
            short8v af[8], bhf[4], blf[4];
#pragma unroll
            for (int m = 0; m < 8; m++) {
                int r = wr * 128 + m * 16 + (l & 15);
                int ch = (s * 4 + (l >> 4)) ^ (r & 7);
                af[m] = *(const short8v*)(As + r * 64 + ch * 8);
            }
#pragma unroll
            for (int n = 0; n < 4; n++) {
                int rb = wc * 64 + n * 16 + (l & 15);
                int ch = (s * 4 + (l >> 4)) ^ (rb & 7);
                bhf[n] = *(const short8v*)(Bh + rb * 64 + ch * 8);
                blf[n] = *(const short8v*)(Bl + rb * 64 + ch * 8);
            }
#pragma unroll
            for (int m = 0; m < 8; m++)
#pragma unroll
                for (int n = 0; n < 4; n++) {
                    acc[m][n] = __builtin_amdgcn_mfma_f32_16x16x32_bf16(af[m], bhf[n], acc[m][n], 0, 0, 0);
                    acc[m][n] = __builtin_amdgcn_mfma_f32_16x16x32_bf16(af[m], blf[n], acc[m][n], 0, 0, 0);
                }
        }
        __syncthreads();
    }

    int lr = l & 15, kc = l >> 4;
    if (MODE == 2) {
        float b1v[4], w2v[4];
#pragma unroll
        for (int n = 0; n < 4; n++) {
            int colc = col0 + wc * 64 + n * 16 + lr;
            b1v[n] = bias[colc];
            w2v[n] = w2[colc];
        }
#pragma unroll
        for (int m = 0; m < 8; m++) {
#pragma unroll
            for (int j = 0; j < 4; j++) {
                float p = 0.f;
#pragma unroll
                for (int n = 0; n < 4; n++) {
                    float v = fmaxf(acc[m][n][j] + b1v[n], 0.f);
                    p = fmaf(v, w2v[n], p);
                }
#pragma unroll
                for (int off = 1; off < 16; off <<= 1) p += __shfl_xor(p, off, 64);
                if (lr == 0) {
                    int row = row0 + wr * 128 + m * 16 + (kc << 2) + j;
                    if (row < M) partial[(size_t)row * 8 + blockIdx.y * 2 + wc] = p;
                }
            }
        }
    } else {
        float bv[4];
#pragma unroll
        for (int n = 0; n < 4; n++) bv[n] = bias[col0 + wc * 64 + n * 16 + lr];
#pragma unroll
        for (int m = 0; m < 8; m++) {
#pragma unroll
            for (int j = 0; j < 4; j++) {
                int row = row0 + wr * 128 + m * 16 + (kc << 2) + j;
                if (row < M) {
#pragma unroll
                    for (int n = 0; n < 4; n++) {
                        float v = acc[m][n][j] + bv[n];
                        if (MODE == 1) v = fmaxf(v, 0.f);
                        C[(size_t)row * 256 + col0 + wc * 64 + n * 16 + lr] = f2bf(v);
                    }
                }
            }
        }
    }
}

// ---------------- gate finisher ----------------
__global__ __launch_bounds__(256) void k_gatefin(const float* __restrict__ partial, const float* __restrict__ b2,
                                                 float* __restrict__ gate) {
    int i = blockIdx.x * 256 + threadIdx.x;
    if (i >= NN) return;
    const float4* p = (const float4*)(partial + (size_t)i * 8);
    float4 u = p[0], v = p[1];
    gate[i] = u.x + u.y + u.z + u.w + v.x + v.y + v.z + v.w + b2[0];
}

// ---------------- fused GraphNorm stats + norm + (relu) + residual, 4-way row-parallel ----------------
__global__ __launch_bounds__(1024) void k_statsnorm(const ushort* __restrict__ y, const int* __restrict__ gstart,
                                                    const float* __restrict__ alpha, const float* __restrict__ gamma,
                                                    const float* __restrict__ beta, ushort* __restrict__ x, int relu) {
    __shared__ float r1[4][256];
    __shared__ float r2[4][256];
    __shared__ float amv[256], ivv[256];
    int g = blockIdx.x, t = threadIdx.x;
    int col = t & 255, rg = t >> 8;          // 4 row-groups x 256 cols
    int s = gstart[g], e = gstart[g + 1];
    int n = e - s;
    if (n <= 0) return;
    float s1 = 0.f, s2 = 0.f;
    for (int r = rg; r < n; r += 4) {
        float v = bf2f(y[(size_t)(s + r) * DIMH + col]);
        s1 += v; s2 = fmaf(v, v, s2);
    }
    r1[rg][col] = s1; r2[rg][col] = s2;
    __syncthreads();
    if (t < 256) {
        float S1 = r1[0][col] + r1[1][col] + r1[2][col] + r1[3][col];
        float S2 = r2[0][col] + r2[1][col] + r2[2][col] + r2[3][col];
        float cnt = (float)(n > 1 ? n : 1);
        float m = S1 / cnt;
        float am = alpha[col] * m;
        float var = S2 / cnt - 2.f * am * m + am * am;
        amv[col] = am;
        ivv[col] = rsqrtf(var + EPSV);
    }
    __syncthreads();
    float am = amv[col], iv = ivv[col];
    float ga = gamma[col], be = beta[col];
    for (int r = rg; r < n; r += 4) {
        size_t idx = (size_t)(s + r) * DIMH + col;
        float v  = bf2f(y[idx]);
        float xo = bf2f(x[idx]);
        float o = (v - am) * iv * ga + be;
        if (relu) o = fmaxf(o, 0.f);
        x[idx] = f2bf(xo + o);
    }
}

// ---------------- segment softmax + weighted pool, 4-way row-parallel ----------------
__global__ __launch_bounds__(1024) void k_pool(const ushort* __restrict__ x, const float* __restrict__ gate,
                                               const int* __restrict__ gstart, float* __restrict__ outg) {
    __shared__ float red[1024];
    __shared__ float wbuf[1024];
    __shared__ float pacc[4][256];
    int g = blockIdx.x, t = threadIdx.x;
    int col = t & 255, rg = t >> 8;
    int s = gstart[g], e = gstart[g + 1];
    int n = e - s;
    if (n <= 0) { if (t < 256) outg[(size_t)g * DIMH + col] = 0.f; return; }
    float m = -3.4e38f;
    for (int i = t; i < n; i += 1024) m = fmaxf(m, gate[s + i]);
    red[t] = m; __syncthreads();
    for (int o = 512; o > 0; o >>= 1) { if (t < o) red[t] = fmaxf(red[t], red[t + o]); __syncthreads(); }
    m = red[0]; __syncthreads();
    float se = 0.f;
    for (int i = t; i < n; i += 1024) se += expf(gate[s + i] - m);
    red[t] = se; __syncthreads();
    for (int o = 512; o > 0; o >>= 1) { if (t < o) red[t] += red[t + o]; __syncthreads(); }
    float inv_se = 1.f / red[0];
    float acc = 0.f;
    for (int base = 0; base < n; base += 1024) {
        __syncthreads();
        int i = base + t;
        if (i < n) wbuf[t] = expf(gate[s + i] - m) * inv_se;
        __syncthreads();
        int cnt = min(1024, n - base);
        for (int r = rg; r < cnt; r += 4)
            acc += wbuf[r] * bf2f(x[(size_t)(s + base + r) * DIMH + col]);
    }
    pacc[rg][col] = acc;
    __syncthreads();
    if (t < 256) outg[(size_t)g * DIMH + col] = pacc[0][col] + pacc[1][col] + pacc[2][col] + pacc[3][col];
}

__global__ __launch_bounds__(256) void k_final(float* __restrict__ out) {
    const int GD = GG * DIMH;
    int i = blockIdx.x * 256 + threadIdx.x;
    if (i >= GD) return;
    float s = out[i] + out[GD + i] + out[2 * GD + i] + out[3 * GD + i];
    out[4 * GD + i] = 0.25f * s;
}

__global__ __launch_bounds__(256) void k_zero_out(float* __restrict__ out, int n) {
    int i = blockIdx.x * 256 + threadIdx.x;
    if (i < n) out[i] = 0.f;
}

// ---------------- host ----------------
extern "C" void kernel_launch(void* const* d_in, const int* in_sizes, int n_in,
                              void* d_out, int out_size, void* d_ws, size_t ws_size,
                              hipStream_t stream) {
    const int*   x_idx     = (const int*)d_in[0];
    const int*   node_dep  = (const int*)d_in[1];
    const int*   eidx      = (const int*)d_in[2];
    const int*   batch     = (const int*)d_in[3];
    const float* emb_node  = (const float*)d_in[4];
    const float* emb_depth = (const float*)d_in[5];
    const float* gin_w1    = (const float*)d_in[6];
    const float* gin_b1    = (const float*)d_in[7];
    const float* gin_w2    = (const float*)d_in[8];
    const float* gin_b2    = (const float*)d_in[9];
    const float* gn_alpha  = (const float*)d_in[10];
    const float* gn_gamma  = (const float*)d_in[11];
    const float* gn_beta   = (const float*)d_in[12];
    const float* att_w1    = (const float*)d_in[13];
    const float* att_b1    = (const float*)d_in[14];
    const float* att_w2    = (const float*)d_in[15];
    const float* att_b2    = (const float*)d_in[16];
    float* out = (float*)d_out;
    (void)in_sizes; (void)n_in;

    const size_t SZ_NODE_BF16 = (size_t)NN * DIMH * 2;      // 51.2 MB
    const size_t SZ_W256 = (size_t)NDEPTH * 256 * 256 * 2;  // 512 KB
    const size_t SZ_W512 = (size_t)NDEPTH * 256 * 512 * 2;  // 1 MB
    size_t required = 3 * ((SZ_NODE_BF16 + 255) & ~(size_t)255)
                    + 4 * SZ_W256 + 2 * SZ_W512
                    + ((size_t)EE * 4 + 256) + ((size_t)(NN + 1) * 4 + 256) * 2
                    + 4096 + 8192 + ((size_t)NN * 4 + 256) + 65536;
    if (ws_size < required) {
        k_zero_out<<<(out_size + 255) / 256, 256, 0, stream>>>(out, out_size);
        return;
    }

    char* w = (char*)d_ws;
    size_t off = 0;
    auto alloc = [&](size_t bytes) -> char* {
        char* p = w + off;
        off += (bytes + 255) & ~(size_t)255;
        return p;
    };
    ushort* x  = (ushort*)alloc(SZ_NODE_BF16);
    ushort* hb = (ushort*)alloc(SZ_NODE_BF16);   // h, then y2
    ushort* y1 = (ushort*)alloc(SZ_NODE_BF16);   // y1; reused as attgate partial f32 [N][8]
    float* partial = (float*)y1;
    ushort* wt_g1h = (ushort*)alloc(SZ_W256);
    ushort* wt_g1l = (ushort*)alloc(SZ_W256);
    ushort* wt_g2h = (ushort*)alloc(SZ_W256);
    ushort* wt_g2l = (ushort*)alloc(SZ_W256);
    ushort* wt_a1h = (ushort*)alloc(SZ_W512);
    ushort* wt_a1l = (ushort*)alloc(SZ_W512);
    int* deg    = (int*)alloc((size_t)NN * 4);   // degree, then cursor
    int* rs     = (int*)alloc((size_t)(NN + 1) * 4);
    int* part   = (int*)alloc(512 * 4);
    int* gstart = (int*)alloc((GG + 1) * 4);
    int* col    = (int*)alloc((size_t)EE * 4);
    float* gate = (float*)alloc((size_t)NN * 4);

    const int* src  = eidx;
    const int* dstp = eidx + EE;

    hipMemsetAsync(deg, 0, (size_t)NN * 4, stream);
    k_graph_bounds<<<(GG + 1 + 255) / 256, 256, 0, stream>>>(batch, gstart);
    k_hist<<<(EE + 255) / 256, 256, 0, stream>>>(dstp, deg);
    int nb = (NN + 255) / 256;   // 391
    k_scan_a<<<nb, 256, 0, stream>>>(deg, rs, part);
    k_scan_b<<<1, 512, 0, stream>>>(part, nb, rs);
    k_scan_c<<<nb, 256, 0, stream>>>(rs, part, deg);   // deg becomes cursor
    k_scatter<<<(EE + 255) / 256, 256, 0, stream>>>(src, dstp, deg, col);
    k_encoder<<<(NN * 64 + 255) / 256, 256, 0, stream>>>(x_idx, node_dep, emb_node, emb_depth, x);

    // weight prep: transpose + hi/lo bf16 split
    k_wtrans<<<dim3(8, 8, NDEPTH), 256, 0, stream>>>(gin_w1, wt_g1h, wt_g1l, 256, 256);
    k_wtrans<<<dim3(8, 8, NDEPTH), 256, 0, stream>>>(gin_w2, wt_g2h, wt_g2l, 256, 256);
    k_wtrans<<<dim3(16, 8, NDEPTH), 256, 0, stream>>>(att_w1, wt_a1h, wt_a1l, 256, 512);

    const int GD = GG * DIMH;
    const int MB = (NN + 255) / 256;   // 391
    for (int d = 0; d < NDEPTH; d++) {
        k_aggregate<<<(NN + 3) / 4, 256, 0, stream>>>(x, rs, col, hb);
        k_gemm64<1><<<dim3(MB, 2), 256, 0, stream>>>(hb, wt_g1h + (size_t)d * 65536, wt_g1l + (size_t)d * 65536,
                                                     gin_b1 + d * 256, nullptr, y1, nullptr, NN);
        k_gemm64<0><<<dim3(MB, 2), 256, 0, stream>>>(y1, wt_g2h + (size_t)d * 65536, wt_g2l + (size_t)d * 65536,
                                                     gin_b2 + d * 256, nullptr, hb, nullptr, NN);
        k_statsnorm<<<GG, 1024, 0, stream>>>(hb, gstart, gn_alpha + d * 256, gn_gamma + d * 256,
                                             gn_beta + d * 256, x, (d < NDEPTH - 1) ? 1 : 0);
        k_gemm64<2><<<dim3(MB, 4), 256, 0, stream>>>(x, wt_a1h + (size_t)d * 131072, wt_a1l + (size_t)d * 131072,
                                                     att_b1 + d * 512, att_w2 + d * 512, nullptr, partial, NN);
        k_gatefin<<<(NN + 255) / 256, 256, 0, stream>>>(partial, att_b2 + d, gate);
        k_pool<<<GG, 1024, 0, stream>>>(x, gate, gstart, out + (size_t)d * GD);
    }
    k_final<<<(GD + 255) / 256, 256, 0, stream>>>(out);
}

// Round 10
// 1595.778 us; speedup vs baseline: 1.8968x; 1.0087x over previous
//
#include <hip/hip_runtime.h>
#include <hip/hip_bf16.h>

#define NN 100000
#define EE 1600000
#define GG 1000
#define DIMH 256
#define NDEPTH 4
static constexpr float EPSV = 1e-5f;

typedef unsigned short ushort;
typedef __attribute__((ext_vector_type(8))) short short8v;
typedef __attribute__((ext_vector_type(4))) float f32x4;

__device__ __forceinline__ float bf2f(ushort u) {
    return __uint_as_float(((unsigned)u) << 16);
}
__device__ __forceinline__ ushort f2bf(float f) {
    unsigned u = __float_as_uint(f);
    unsigned r = u + 0x7FFFu + ((u >> 16) & 1u);   // RNE
    return (ushort)(r >> 16);
}

#define GLOAD16(g, s) __builtin_amdgcn_global_load_lds((const __attribute__((address_space(1))) void*)(g), \
                      (__attribute__((address_space(3))) void*)(s), 16, 0, 0)

// ---------------- CSR build ----------------
__global__ __launch_bounds__(256) void k_graph_bounds(const int* __restrict__ batch, int* __restrict__ gstart) {
    int g = blockIdx.x * 256 + threadIdx.x;
    if (g > GG) return;
    int lo = 0, hi = NN;
    while (lo < hi) { int mid = (lo + hi) >> 1; if (batch[mid] < g) lo = mid + 1; else hi = mid; }
    gstart[g] = lo;
}

__global__ __launch_bounds__(256) void k_hist(const int* __restrict__ dst, int* __restrict__ deg) {
    int e = blockIdx.x * 256 + threadIdx.x;
    if (e < EE) atomicAdd(&deg[dst[e]], 1);
}

__global__ __launch_bounds__(256) void k_scan_a(const int* __restrict__ deg, int* __restrict__ rs, int* __restrict__ part) {
    __shared__ int s[256];
    int t = threadIdx.x;
    int i = blockIdx.x * 256 + t;
    int v = (i < NN) ? deg[i] : 0;
    s[t] = v; __syncthreads();
    for (int off = 1; off < 256; off <<= 1) {
        int u = (t >= off) ? s[t - off] : 0;
        __syncthreads();
        s[t] += u;
        __syncthreads();
    }
    if (i < NN) rs[i] = s[t] - v;
    if (t == 255) part[blockIdx.x] = s[255];
}

__global__ __launch_bounds__(512) void k_scan_b(int* __restrict__ part, int nb, int* __restrict__ rs) {
    __shared__ int s[512];
    int t = threadIdx.x;
    int v = (t < nb) ? part[t] : 0;
    s[t] = v; __syncthreads();
    for (int off = 1; off < 512; off <<= 1) {
        int u = (t >= off) ? s[t - off] : 0;
        __syncthreads();
        s[t] += u;
        __syncthreads();
    }
    if (t < nb) part[t] = s[t] - v;  // exclusive
    if (t == 0) rs[NN] = EE;
}

// finalize row starts AND copy to cursor
__global__ __launch_bounds__(256) void k_scan_c(int* __restrict__ rs, const int* __restrict__ part,
                                                int* __restrict__ cursor) {
    int i = blockIdx.x * 256 + threadIdx.x;
    if (i < NN) {
        int v = rs[i] + part[blockIdx.x];
        rs[i] = v;
        cursor[i] = v;
    }
}

__global__ __launch_bounds__(256) void k_scatter(const int* __restrict__ src, const int* __restrict__ dst,
                                                 int* __restrict__ cursor, int* __restrict__ col) {
    int e = blockIdx.x * 256 + threadIdx.x;
    if (e >= EE) return;
    int d = dst[e];
    int pos = atomicAdd(&cursor[d], 1);
    col[pos] = src[e];
}

// ---------------- weight transpose + bf16 split: W[K][N] f32 -> Wt_hi/lo[N][K] bf16 ----------------
__global__ __launch_bounds__(256) void k_wtrans(const float* __restrict__ in, ushort* __restrict__ out_hi,
                                                ushort* __restrict__ out_lo, int K, int N) {
    int d = blockIdx.z;
    in  += (size_t)d * K * N;
    out_hi += (size_t)d * K * N;
    out_lo += (size_t)d * K * N;
    int n0 = blockIdx.x * 32, k0 = blockIdx.y * 32;
    int t = threadIdx.x;
    int tx = t & 31, ty = t >> 5;      // ty 0..7
    __shared__ float tile[32][33];
#pragma unroll
    for (int j = 0; j < 4; j++) tile[ty + 8 * j][tx] = in[(size_t)(k0 + ty + 8 * j) * N + n0 + tx];
    __syncthreads();
#pragma unroll
    for (int j = 0; j < 4; j++) {
        float f = tile[tx][ty + 8 * j];
        ushort hi = f2bf(f);
        float lo = f - bf2f(hi);
        size_t o = (size_t)(n0 + ty + 8 * j) * K + k0 + tx;
        out_hi[o] = hi;
        out_lo[o] = f2bf(lo);
    }
}

// ---------------- node encoder ----------------
__global__ __launch_bounds__(256) void k_encoder(const int* __restrict__ xidx, const int* __restrict__ ndep,
                                                 const float* __restrict__ en, const float* __restrict__ ed,
                                                 ushort* __restrict__ x) {
    int gi = blockIdx.x * 256 + threadIdx.x;     // = node*64 + q
    int node = gi >> 6, q = gi & 63;
    if (node >= NN) return;
    float4 va = ((const float4*)en)[(size_t)xidx[node] * 64 + q];
    float4 vb = ((const float4*)ed)[(size_t)ndep[node] * 64 + q];
    ushort4 o;
    o.x = f2bf(va.x + vb.x); o.y = f2bf(va.y + vb.y);
    o.z = f2bf(va.z + vb.z); o.w = f2bf(va.w + vb.w);
    ((ushort4*)x)[gi] = o;
}

// ---------------- GIN aggregate (8 gathers in flight, 4 accumulator chains) ----------------
__global__ __launch_bounds__(256) void k_aggregate(const ushort* __restrict__ x, const int* __restrict__ rs,
                                                   const int* __restrict__ col, ushort* __restrict__ hb) {
    int node = blockIdx.x * 4 + (threadIdx.x >> 6);
    int lane = threadIdx.x & 63;
    if (node >= NN) return;
    const ushort4* x4 = (const ushort4*)x;
    ushort4 sv = x4[(size_t)node * 64 + lane];
    float a0 = bf2f(sv.x), a1 = bf2f(sv.y), a2 = bf2f(sv.z), a3 = bf2f(sv.w);
    float b0 = 0.f, b1 = 0.f, b2 = 0.f, b3 = 0.f;
    float c0 = 0.f, c1 = 0.f, c2 = 0.f, c3 = 0.f;
    float d0 = 0.f, d1 = 0.f, d2 = 0.f, d3 = 0.f;
    int s = rs[node], e = rs[node + 1];
    int j = s;
    for (; j + 8 <= e; j += 8) {
        int i0 = col[j], i1 = col[j + 1], i2 = col[j + 2], i3 = col[j + 3];
        int i4 = col[j + 4], i5 = col[j + 5], i6 = col[j + 6], i7 = col[j + 7];
        ushort4 v0 = x4[(size_t)i0 * 64 + lane];
        ushort4 v1 = x4[(size_t)i1 * 64 + lane];
        ushort4 v2 = x4[(size_t)i2 * 64 + lane];
        ushort4 v3 = x4[(size_t)i3 * 64 + lane];
        ushort4 v4 = x4[(size_t)i4 * 64 + lane];
        ushort4 v5 = x4[(size_t)i5 * 64 + lane];
        ushort4 v6 = x4[(size_t)i6 * 64 + lane];
        ushort4 v7 = x4[(size_t)i7 * 64 + lane];
        a0 += bf2f(v0.x); a1 += bf2f(v0.y); a2 += bf2f(v0.z); a3 += bf2f(v0.w);
        b0 += bf2f(v1.x); b1 += bf2f(v1.y); b2 += bf2f(v1.z); b3 += bf2f(v1.w);
        c0 += bf2f(v2.x); c1 += bf2f(v2.y); c2 += bf2f(v2.z); c3 += bf2f(v2.w);
        d0 += bf2f(v3.x); d1 += bf2f(v3.y); d2 += bf2f(v3.z); d3 += bf2f(v3.w);
        a0 += bf2f(v4.x); a1 += bf2f(v4.y); a2 += bf2f(v4.z); a3 += bf2f(v4.w);
        b0 += bf2f(v5.x); b1 += bf2f(v5.y); b2 += bf2f(v5.z); b3 += bf2f(v5.w);
        c0 += bf2f(v6.x); c1 += bf2f(v6.y); c2 += bf2f(v6.z); c3 += bf2f(v6.w);
        d0 += bf2f(v7.x); d1 += bf2f(v7.y); d2 += bf2f(v7.z); d3 += bf2f(v7.w);
    }
    for (; j + 4 <= e; j += 4) {
        int i0 = col[j], i1 = col[j + 1], i2 = col[j + 2], i3 = col[j + 3];
        ushort4 v0 = x4[(size_t)i0 * 64 + lane];
        ushort4 v1 = x4[(size_t)i1 * 64 + lane];
        ushort4 v2 = x4[(size_t)i2 * 64 + lane];
        ushort4 v3 = x4[(size_t)i3 * 64 + lane];
        a0 += bf2f(v0.x); a1 += bf2f(v0.y); a2 += bf2f(v0.z); a3 += bf2f(v0.w);
        b0 += bf2f(v1.x); b1 += bf2f(v1.y); b2 += bf2f(v1.z); b3 += bf2f(v1.w);
        c0 += bf2f(v2.x); c1 += bf2f(v2.y); c2 += bf2f(v2.z); c3 += bf2f(v2.w);
        d0 += bf2f(v3.x); d1 += bf2f(v3.y); d2 += bf2f(v3.z); d3 += bf2f(v3.w);
    }
    for (; j < e; j++) {
        int c = col[j];
        ushort4 v = x4[(size_t)c * 64 + lane];
        a0 += bf2f(v.x); a1 += bf2f(v.y); a2 += bf2f(v.z); a3 += bf2f(v.w);
    }
    a0 += b0 + c0 + d0; a1 += b1 + c1 + d1; a2 += b2 + c2 + d2; a3 += b3 + c3 + d3;
    ushort4 o; o.x = f2bf(a0); o.y = f2bf(a1); o.z = f2bf(a2); o.w = f2bf(a3);
    ((ushort4*)hb)[(size_t)node * 64 + lane] = o;
}

// ============ GEMM v4: block 256x128, 4 waves of 128x64, K_STEP=64, stage->barrier->compute ============
// MODE 0: bias, store bf16.  MODE 1: bias+relu, store bf16.  MODE 2: attgate partial -> partial[row][by*2+wc]
template<int MODE>
__global__ __launch_bounds__(256, 2) void k_gemm64(const ushort* __restrict__ A,
                                                   const ushort* __restrict__ Bhi,
                                                   const ushort* __restrict__ Blo,
                                                   const float* __restrict__ bias,
                                                   const float* __restrict__ w2,
                                                   ushort* __restrict__ C,
                                                   float* __restrict__ partial,
                                                   int M) {
    __shared__ __align__(16) ushort As[256 * 64];   // 32 KB
    __shared__ __align__(16) ushort Bh[128 * 64];   // 16 KB
    __shared__ __align__(16) ushort Bl[128 * 64];   // 16 KB
    int t = threadIdx.x;
    int wv = t >> 6, l = t & 63;
    int wr = wv >> 1, wc = wv & 1;
    int row0 = blockIdx.x * 256;
    int col0 = blockIdx.y * 128;

    f32x4 acc[8][4];
#pragma unroll
    for (int m = 0; m < 8; m++)
#pragma unroll
        for (int n = 0; n < 4; n++) acc[m][n] = (f32x4){0.f, 0.f, 0.f, 0.f};

    int srow_in = l >> 3;       // 0..7
    int slot    = l & 7;        // 16B chunk slot within a 128B row

    for (int k0 = 0; k0 < 256; k0 += 64) {
#pragma unroll
        for (int i = 0; i < 8; i++) {
            int stripe = wv * 8 + i;                // 0..31
            int rl = stripe * 8 + srow_in;          // 0..255
            int gc = slot ^ (rl & 7);               // pre-swizzled global chunk
            const ushort* ga = A + (size_t)min(row0 + rl, M - 1) * 256 + k0 + gc * 8;
            GLOAD16(ga, As + stripe * 512 + l * 8);
        }
#pragma unroll
        for (int i = 0; i < 4; i++) {
            int stripe = wv * 4 + i;                // 0..15
            int rl = stripe * 8 + srow_in;          // 0..127
            int gc = slot ^ (rl & 7);
            const ushort* gh = Bhi + (size_t)(col0 + rl) * 256 + k0 + gc * 8;
            GLOAD16(gh, Bh + stripe * 512 + l * 8);
            const ushort* gl = Blo + (size_t)(col0 + rl) * 256 + k0 + gc * 8;
            GLOAD16(gl, Bl + stripe * 512 + l * 8);
        }
        __syncthreads();
#pragma unroll
        for (int s = 0; s < 2; s++) {
            short8v af[8], bhf[4], blf[4];
#pragma unroll
            for (int m = 0; m < 8; m++) {
                int r = wr * 128 + m * 16 + (l & 15);
                int ch = (s * 4 + (l >> 4)) ^ (r & 7);
                af[m] = *(const short8v*)(As + r * 64 + ch * 8);
            }
#pragma unroll
            for (int n = 0; n < 4; n++) {
                int rb = wc * 64 + n * 16 + (l & 15);
                int ch = (s * 4 + (l >> 4)) ^ (rb & 7);
                bhf[n] = *(const short8v*)(Bh + rb * 64 + ch * 8);
                blf[n] = *(const short8v*)(Bl + rb * 64 + ch * 8);
            }
#pragma unroll
            for (int m = 0; m < 8; m++)
#pragma unroll
                for (int n = 0; n < 4; n++) {
                    acc[m][n] = __builtin_amdgcn_mfma_f32_16x16x32_bf16(af[m], bhf[n], acc[m][n], 0, 0, 0);
                    acc[m][n] = __builtin_amdgcn_mfma_f32_16x16x32_bf16(af[m], blf[n], acc[m][n], 0, 0, 0);
                }
        }
        __syncthreads();
    }

    int lr = l & 15, kc = l >> 4;
    if (MODE == 2) {
        float b1v[4], w2v[4];
#pragma unroll
        for (int n = 0; n < 4; n++) {
            int colc = col0 + wc * 64 + n * 16 + lr;
            b1v[n] = bias[colc];
            w2v[n] = w2[colc];
        }
#pragma unroll
        for (int m = 0; m < 8; m++) {
#pragma unroll
            for (int j = 0; j < 4; j++) {
                float p = 0.f;
#pragma unroll
                for (int n = 0; n < 4; n++) {
                    float v = fmaxf(acc[m][n][j] + b1v[n], 0.f);
                    p = fmaf(v, w2v[n], p);
                }
#pragma unroll
                for (int off = 1; off < 16; off <<= 1) p += __shfl_xor(p, off, 64);
                if (lr == 0) {
                    int row = row0 + wr * 128 + m * 16 + (kc << 2) + j;
                    if (row < M) partial[(size_t)row * 8 + blockIdx.y * 2 + wc] = p;
                }
            }
        }
    } else {
        float bv[4];
#pragma unroll
        for (int n = 0; n < 4; n++) bv[n] = bias[col0 + wc * 64 + n * 16 + lr];
#pragma unroll
        for (int m = 0; m < 8; m++) {
#pragma unroll
            for (int j = 0; j < 4; j++) {
                int row = row0 + wr * 128 + m * 16 + (kc << 2) + j;
                if (row < M) {
#pragma unroll
                    for (int n = 0; n < 4; n++) {
                        float v = acc[m][n][j] + bv[n];
                        if (MODE == 1) v = fmaxf(v, 0.f);
                        C[(size_t)row * 256 + col0 + wc * 64 + n * 16 + lr] = f2bf(v);
                    }
                }
            }
        }
    }
}

// ---------------- fused GraphNorm stats + norm + (relu) + residual, 4-way row-parallel ----------------
__global__ __launch_bounds__(1024) void k_statsnorm(const ushort* __restrict__ y, const int* __restrict__ gstart,
                                                    const float* __restrict__ alpha, const float* __restrict__ gamma,
                                                    const float* __restrict__ beta, ushort* __restrict__ x, int relu) {
    __shared__ float r1[4][256];
    __shared__ float r2[4][256];
    __shared__ float amv[256], ivv[256];
    int g = blockIdx.x, t = threadIdx.x;
    int col = t & 255, rg = t >> 8;          // 4 row-groups x 256 cols
    int s = gstart[g], e = gstart[g + 1];
    int n = e - s;
    if (n <= 0) return;
    float s1 = 0.f, s2 = 0.f;
    for (int r = rg; r < n; r += 4) {
        float v = bf2f(y[(size_t)(s + r) * DIMH + col]);
        s1 += v; s2 = fmaf(v, v, s2);
    }
    r1[rg][col] = s1; r2[rg][col] = s2;
    __syncthreads();
    if (t < 256) {
        float S1 = r1[0][col] + r1[1][col] + r1[2][col] + r1[3][col];
        float S2 = r2[0][col] + r2[1][col] + r2[2][col] + r2[3][col];
        float cnt = (float)(n > 1 ? n : 1);
        float m = S1 / cnt;
        float am = alpha[col] * m;
        float var = S2 / cnt - 2.f * am * m + am * am;
        amv[col] = am;
        ivv[col] = rsqrtf(var + EPSV);
    }
    __syncthreads();
    float am = amv[col], iv = ivv[col];
    float ga = gamma[col], be = beta[col];
    for (int r = rg; r < n; r += 4) {
        size_t idx = (size_t)(s + r) * DIMH + col;
        float v  = bf2f(y[idx]);
        float xo = bf2f(x[idx]);
        float o = (v - am) * iv * ga + be;
        if (relu) o = fmaxf(o, 0.f);
        x[idx] = f2bf(xo + o);
    }
}

// ---------------- fused gate + segment softmax + weighted pool, 4-way row-parallel ----------------
// gate[i] = sum8(partial[i]) + b2  (bit-identical to the old k_gatefin expression)
__global__ __launch_bounds__(1024) void k_pool(const ushort* __restrict__ x, const float* __restrict__ partial,
                                               const float* __restrict__ b2, const int* __restrict__ gstart,
                                               float* __restrict__ outg) {
    __shared__ float gbuf[1024];
    __shared__ float red[1024];
    __shared__ float wbuf[1024];
    __shared__ float pacc[4][256];
    int g = blockIdx.x, t = threadIdx.x;
    int col = t & 255, rg = t >> 8;
    int s = gstart[g], e = gstart[g + 1];
    int n = e - s;
    if (n <= 0) { if (t < 256) outg[(size_t)g * DIMH + col] = 0.f; return; }
    float b2v = b2[0];
    auto gcomp = [&](int i) -> float {
        const float4* p = (const float4*)(partial + (size_t)(s + i) * 8);
        float4 u = p[0], v = p[1];
        return u.x + u.y + u.z + u.w + v.x + v.y + v.z + v.w + b2v;
    };
    if (t < n && t < 1024) gbuf[t] = gcomp(t);   // n <= ~150 in practice
    __syncthreads();
    auto gval = [&](int i) -> float { return (i < 1024) ? gbuf[i] : gcomp(i); };
    float m = -3.4e38f;
    for (int i = t; i < n; i += 1024) m = fmaxf(m, gval(i));
    red[t] = m; __syncthreads();
    for (int o = 512; o > 0; o >>= 1) { if (t < o) red[t] = fmaxf(red[t], red[t + o]); __syncthreads(); }
    m = red[0]; __syncthreads();
    float se = 0.f;
    for (int i = t; i < n; i += 1024) se += expf(gval(i) - m);
    red[t] = se; __syncthreads();
    for (int o = 512; o > 0; o >>= 1) { if (t < o) red[t] += red[t + o]; __syncthreads(); }
    float inv_se = 1.f / red[0];
    float acc = 0.f;
    for (int base = 0; base < n; base += 1024) {
        __syncthreads();
        int i = base + t;
        if (i < n) wbuf[t] = expf(gval(i) - m) * inv_se;
        __syncthreads();
        int cnt = min(1024, n - base);
        for (int r = rg; r < cnt; r += 4)
            acc += wbuf[r] * bf2f(x[(size_t)(s + base + r) * DIMH + col]);
    }
    pacc[rg][col] = acc;
    __syncthreads();
    if (t < 256) outg[(size_t)g * DIMH + col] = pacc[0][col] + pacc[1][col] + pacc[2][col] + pacc[3][col];
}

__global__ __launch_bounds__(256) void k_final(float* __restrict__ out) {
    const int GD = GG * DIMH;
    int i = blockIdx.x * 256 + threadIdx.x;
    if (i >= GD) return;
    float s = out[i] + out[GD + i] + out[2 * GD + i] + out[3 * GD + i];
    out[4 * GD + i] = 0.25f * s;
}

__global__ __launch_bounds__(256) void k_zero_out(float* __restrict__ out, int n) {
    int i = blockIdx.x * 256 + threadIdx.x;
    if (i < n) out[i] = 0.f;
}

// ---------------- host ----------------
extern "C" void kernel_launch(void* const* d_in, const int* in_sizes, int n_in,
                              void* d_out, int out_size, void* d_ws, size_t ws_size,
                              hipStream_t stream) {
    const int*   x_idx     = (const int*)d_in[0];
    const int*   node_dep  = (const int*)d_in[1];
    const int*   eidx      = (const int*)d_in[2];
    const int*   batch     = (const int*)d_in[3];
    const float* emb_node  = (const float*)d_in[4];
    const float* emb_depth = (const float*)d_in[5];
    const float* gin_w1    = (const float*)d_in[6];
    const float* gin_b1    = (const float*)d_in[7];
    const float* gin_w2    = (const float*)d_in[8];
    const float* gin_b2    = (const float*)d_in[9];
    const float* gn_alpha  = (const float*)d_in[10];
    const float* gn_gamma  = (const float*)d_in[11];
    const float* gn_beta   = (const float*)d_in[12];
    const float* att_w1    = (const float*)d_in[13];
    const float* att_b1    = (const float*)d_in[14];
    const float* att_w2    = (const float*)d_in[15];
    const float* att_b2    = (const float*)d_in[16];
    float* out = (float*)d_out;
    (void)in_sizes; (void)n_in;

    const size_t SZ_NODE_BF16 = (size_t)NN * DIMH * 2;      // 51.2 MB
    const size_t SZ_W256 = (size_t)NDEPTH * 256 * 256 * 2;  // 512 KB
    const size_t SZ_W512 = (size_t)NDEPTH * 256 * 512 * 2;  // 1 MB
    size_t required = 3 * ((SZ_NODE_BF16 + 255) & ~(size_t)255)
                    + 4 * SZ_W256 + 2 * SZ_W512
                    + ((size_t)EE * 4 + 256) + ((size_t)(NN + 1) * 4 + 256) * 2
                    + 4096 + 8192 + ((size_t)NN * 4 + 256) + 65536;
    if (ws_size < required) {
        k_zero_out<<<(out_size + 255) / 256, 256, 0, stream>>>(out, out_size);
        return;
    }

    char* w = (char*)d_ws;
    size_t off = 0;
    auto alloc = [&](size_t bytes) -> char* {
        char* p = w + off;
        off += (bytes + 255) & ~(size_t)255;
        return p;
    };
    ushort* x  = (ushort*)alloc(SZ_NODE_BF16);
    ushort* hb = (ushort*)alloc(SZ_NODE_BF16);   // h, then y2
    ushort* y1 = (ushort*)alloc(SZ_NODE_BF16);   // y1; reused as attgate partial f32 [N][8]
    float* partial = (float*)y1;
    ushort* wt_g1h = (ushort*)alloc(SZ_W256);
    ushort* wt_g1l = (ushort*)alloc(SZ_W256);
    ushort* wt_g2h = (ushort*)alloc(SZ_W256);
    ushort* wt_g2l = (ushort*)alloc(SZ_W256);
    ushort* wt_a1h = (ushort*)alloc(SZ_W512);
    ushort* wt_a1l = (ushort*)alloc(SZ_W512);
    int* deg    = (int*)alloc((size_t)NN * 4);   // degree, then cursor
    int* rs     = (int*)alloc((size_t)(NN + 1) * 4);
    int* part   = (int*)alloc(512 * 4);
    int* gstart = (int*)alloc((GG + 1) * 4);
    int* col    = (int*)alloc((size_t)EE * 4);

    const int* src  = eidx;
    const int* dstp = eidx + EE;

    hipMemsetAsync(deg, 0, (size_t)NN * 4, stream);
    k_graph_bounds<<<(GG + 1 + 255) / 256, 256, 0, stream>>>(batch, gstart);
    k_hist<<<(EE + 255) / 256, 256, 0, stream>>>(dstp, deg);
    int nb = (NN + 255) / 256;   // 391
    k_scan_a<<<nb, 256, 0, stream>>>(deg, rs, part);
    k_scan_b<<<1, 512, 0, stream>>>(part, nb, rs);
    k_scan_c<<<nb, 256, 0, stream>>>(rs, part, deg);   // deg becomes cursor
    k_scatter<<<(EE + 255) / 256, 256, 0, stream>>>(src, dstp, deg, col);
    k_encoder<<<(NN * 64 + 255) / 256, 256, 0, stream>>>(x_idx, node_dep, emb_node, emb_depth, x);

    // weight prep: transpose + hi/lo bf16 split
    k_wtrans<<<dim3(8, 8, NDEPTH), 256, 0, stream>>>(gin_w1, wt_g1h, wt_g1l, 256, 256);
    k_wtrans<<<dim3(8, 8, NDEPTH), 256, 0, stream>>>(gin_w2, wt_g2h, wt_g2l, 256, 256);
    k_wtrans<<<dim3(16, 8, NDEPTH), 256, 0, stream>>>(att_w1, wt_a1h, wt_a1l, 256, 512);

    const int GD = GG * DIMH;
    const int MB = (NN + 255) / 256;   // 391
    for (int d = 0; d < NDEPTH; d++) {
        k_aggregate<<<(NN + 3) / 4, 256, 0, stream>>>(x, rs, col, hb);
        k_gemm64<1><<<dim3(MB, 2), 256, 0, stream>>>(hb, wt_g1h + (size_t)d * 65536, wt_g1l + (size_t)d * 65536,
                                                     gin_b1 + d * 256, nullptr, y1, nullptr, NN);
        k_gemm64<0><<<dim3(MB, 2), 256, 0, stream>>>(y1, wt_g2h + (size_t)d * 65536, wt_g2l + (size_t)d * 65536,
                                                     gin_b2 + d * 256, nullptr, hb, nullptr, NN);
        k_statsnorm<<<GG, 1024, 0, stream>>>(hb, gstart, gn_alpha + d * 256, gn_gamma + d * 256,
                                             gn_beta + d * 256, x, (d < NDEPTH - 1) ? 1 : 0);
        k_gemm64<2><<<dim3(MB, 4), 256, 0, stream>>>(x, wt_a1h + (size_t)d * 131072, wt_a1l + (size_t)d * 131072,
                                                     att_b1 + d * 512, att_w2 + d * 512, nullptr, partial, NN);
        k_pool<<<GG, 1024, 0, stream>>>(x, partial, att_b2 + d, gstart, out + (size_t)d * GD);
    }
    k_final<<<(GD + 255) / 256, 256, 0, stream>>>(out);
}